// Round 5
// baseline (2945.553 us; speedup 1.0000x reference)
//
#include <hip/hip_runtime.h>
#include <float.h>

#define BB   8
#define NN   4096
#define SS   2048
#define KK   16
#define MID  32
#define COUT 64
#define CAT  67            // 3 + 64
#define M1   (BB*NN)       // 32768
#define M2   (BB*SS)       // 16384
#define EPSB 1e-5f

// ---- workspace layout (float offsets) ----
#define WS_RED1  0                       // 12 floats  (Sx[3], C[6])
#define WS_RED2  16                      // 128 floats (sum[64], sumsq[64])
#define WS_FPS   512                     // 16384 ints
#define WS_FEATS (512 + 16384)           // 32768*64 floats
#define WS_POOL  (WS_FEATS + M1*COUT)    // 16384*67 floats

// ---------------- K1: input moments for BN1 stats ----------------
__global__ __launch_bounds__(256) void k1_stats(const float* __restrict__ xin,
                                                float* __restrict__ ws) {
    int t = blockIdx.x * 256 + threadIdx.x;
    float r[9];
#pragma unroll
    for (int q = 0; q < 9; q++) r[q] = 0.f;
    for (int p = t; p < M1; p += 64 * 256) {
        float x0 = xin[3 * p], x1 = xin[3 * p + 1], x2 = xin[3 * p + 2];
        r[0] += x0; r[1] += x1; r[2] += x2;
        r[3] = fmaf(x0, x0, r[3]); r[4] = fmaf(x0, x1, r[4]); r[5] = fmaf(x0, x2, r[5]);
        r[6] = fmaf(x1, x1, r[6]); r[7] = fmaf(x1, x2, r[7]); r[8] = fmaf(x2, x2, r[8]);
    }
#pragma unroll
    for (int m = 32; m; m >>= 1) {
#pragma unroll
        for (int q = 0; q < 9; q++) r[q] += __shfl_down(r[q], m, 64);
    }
    if ((threadIdx.x & 63) == 0) {
#pragma unroll
        for (int q = 0; q < 9; q++) atomicAdd(ws + WS_RED1 + q, r[q]);
    }
}

// ---------------- K3: feats = conv2(relu(bn(conv1(x)))), BN prep fused ----------------
__global__ __launch_bounds__(256) void k3_feats(const float* __restrict__ xin,
                                                const float* __restrict__ W1,
                                                const float* __restrict__ b1,
                                                const float* __restrict__ g1,
                                                const float* __restrict__ be1,
                                                const float* __restrict__ W2,
                                                const float* __restrict__ b2,
                                                float* __restrict__ ws) {
    __shared__ float W1s[96], abv[64], W2s[2048], b2s[64];
    int tid = threadIdx.x;
    for (int j = tid; j < 96; j += 256) W1s[j] = W1[j];
    if (tid < 64) b2s[tid] = b2[tid];
    for (int j = tid; j < 2048; j += 256) W2s[j] = W2[j];
    if (tid < MID) {
        const float* r = ws + WS_RED1;
        float S0 = r[0], S1 = r[1], S2 = r[2];
        float C00 = r[3], C01 = r[4], C02 = r[5], C11 = r[6], C12 = r[7], C22 = r[8];
        float w0 = W1[3 * tid], w1 = W1[3 * tid + 1], w2 = W1[3 * tid + 2];
        float invM = 1.f / (float)M1;
        float meanc = (w0 * S0 + w1 * S1 + w2 * S2) * invM;   // mean of Wx (no bias)
        float wCw = w0 * w0 * C00 + w1 * w1 * C11 + w2 * w2 * C22 +
                    2.f * (w0 * w1 * C01 + w0 * w2 * C02 + w1 * w2 * C12);
        float var = wCw * invM - meanc * meanc;                // bias-invariant
        float a = g1[tid] * rsqrtf(var + EPSB);
        abv[tid] = a;
        abv[MID + tid] = be1[tid] - meanc * a;
    }
    __syncthreads();
    int p = blockIdx.x * 256 + tid;
    float x0 = xin[3 * p], x1 = xin[3 * p + 1], x2 = xin[3 * p + 2];
    float h[MID];
#pragma unroll
    for (int o = 0; o < MID; o++) {
        float y = fmaf(W1s[3 * o + 2], x2, fmaf(W1s[3 * o + 1], x1, W1s[3 * o] * x0));
        h[o] = fmaxf(0.f, fmaf(abv[o], y, abv[MID + o]));
    }
    float* fo = ws + WS_FEATS + (size_t)p * COUT;
#pragma unroll
    for (int j = 0; j < COUT; j += 4) {
        float a0 = b2s[j], a1v = b2s[j + 1], a2v = b2s[j + 2], a3v = b2s[j + 3];
#pragma unroll
        for (int o = 0; o < MID; o++) {
            float hv = h[o];
            a0  = fmaf(W2s[(j)     * MID + o], hv, a0);
            a1v = fmaf(W2s[(j + 1) * MID + o], hv, a1v);
            a2v = fmaf(W2s[(j + 2) * MID + o], hv, a2v);
            a3v = fmaf(W2s[(j + 3) * MID + o], hv, a3v);
        }
        *(float4*)(fo + j) = make_float4(a0, a1v, a2v, a3v);
    }
}

// ---------------- K4: FPS — 4 waves, 16 pts/lane, LDS fidx, f32 DPP reduce ----------------
__device__ __forceinline__ unsigned long long u64max(unsigned long long a,
                                                     unsigned long long b) {
    return a > b ? a : b;
}

template <int CTRL>
__device__ __forceinline__ float dppmaxf(float v) {
    int o = __builtin_amdgcn_update_dpp(0, __float_as_int(v), CTRL, 0xF, 0xF, false);
    return fmaxf(v, __int_as_float(o));
}

template <int CTRL>
__device__ __forceinline__ unsigned dppminu(unsigned v) {
    unsigned o = (unsigned)__builtin_amdgcn_update_dpp(0, (int)v, CTRL, 0xF, 0xF, false);
    return v < o ? v : o;
}

__global__ __launch_bounds__(256) void k4_fps(const float* __restrict__ xin,
                                              float* __restrict__ ws) {
    __shared__ float4 Pc[NN];                 // 64 KB centroid lookup
    __shared__ __align__(16) unsigned long long svbuf[2][4];
    __shared__ int fbuf[SS];                  // 8 KB result staging
    int b = blockIdx.x, tid = threadIdx.x;
    const float* xb = xin + (size_t)b * NN * 3;
    float px[16], py[16], pz[16], dist[16];
#pragma unroll
    for (int k = 0; k < 16; k++) {
        int i = tid + (k << 8);
        float x = xb[3 * i], y = xb[3 * i + 1], z = xb[3 * i + 2];
        px[k] = x; py[k] = y; pz[k] = z; dist[k] = FLT_MAX;
        Pc[i] = make_float4(x, y, z, 0.f);
    }
    if (tid == 0) fbuf[0] = 0;
    __syncthreads();
    float4 c0 = Pc[0];
    float cx = c0.x, cy = c0.y, cz = c0.z;
    int wid = tid >> 6, lane = tid & 63;
    int a16 = ((lane ^ 16) << 2), a32 = ((lane ^ 32) << 2), a48 = ((lane ^ 48) << 2);
    for (int t = 1; t < SS; t++) {
        float nd[16];
#pragma unroll
        for (int k = 0; k < 16; k++) {          // independent distance updates
            float dx = px[k] - cx, dy = py[k] - cy, dz = pz[k] - cz;
            float d = fmaf(dz, dz, fmaf(dy, dy, dx * dx));
            nd[k] = fminf(dist[k], d);
            dist[k] = nd[k];
        }
        // depth-4 argmax tree (ties between lanes resolved exactly below;
        // in-lane exact fp ties are measure-zero for this fixed input)
        float v[8]; int ki[8];
#pragma unroll
        for (int j = 0; j < 8; j++) {
            bool s = nd[j + 8] > nd[j];
            v[j] = s ? nd[j + 8] : nd[j]; ki[j] = s ? j + 8 : j;
        }
#pragma unroll
        for (int j = 0; j < 4; j++) {
            bool s = v[j + 4] > v[j];
            v[j] = s ? v[j + 4] : v[j]; ki[j] = s ? ki[j + 4] : ki[j];
        }
        { bool s = v[2] > v[0]; v[0] = s ? v[2] : v[0]; ki[0] = s ? ki[2] : ki[0]; }
        { bool s = v[3] > v[1]; v[1] = s ? v[3] : v[1]; ki[1] = s ? ki[3] : ki[1]; }
        bool s01 = v[1] > v[0];
        float bv = s01 ? v[1] : v[0];
        int   bk = s01 ? ki[1] : ki[0];
        int bi = tid + (bk << 8);
        // wave max (value): 16-lane DPP then 3 bpermute row merges
        float m = bv;
        m = dppmaxf<0xB1>(m);
        m = dppmaxf<0x4E>(m);
        m = dppmaxf<0x141>(m);
        m = dppmaxf<0x140>(m);
        int mi = __float_as_int(m);
        int r16 = __builtin_amdgcn_ds_bpermute(a16, mi);
        int r32 = __builtin_amdgcn_ds_bpermute(a32, mi);
        int r48 = __builtin_amdgcn_ds_bpermute(a48, mi);
        m = fmaxf(fmaxf(m, __int_as_float(r16)),
                  fmaxf(__int_as_float(r32), __int_as_float(r48)));
        // resolve index: lowest point-index among lanes holding the max
        unsigned long long mask = __ballot(bv == m);
        int widx;
        if (__popcll(mask) == 1) {
            int w = __ffsll(mask) - 1;
            widx = __builtin_amdgcn_readlane(bi, w);
        } else {                    // rare exact-tie path: exact u32 min reduce
            unsigned cnd = (bv == m) ? (unsigned)bi : 0xffffffffu;
            cnd = dppminu<0xB1>(cnd); cnd = dppminu<0x4E>(cnd);
            cnd = dppminu<0x141>(cnd); cnd = dppminu<0x140>(cnd);
            unsigned c16 = (unsigned)__builtin_amdgcn_ds_bpermute(a16, (int)cnd);
            unsigned c32 = (unsigned)__builtin_amdgcn_ds_bpermute(a32, (int)cnd);
            unsigned c48 = (unsigned)__builtin_amdgcn_ds_bpermute(a48, (int)cnd);
            cnd = cnd < c16 ? cnd : c16;
            cnd = cnd < c32 ? cnd : c32;
            cnd = cnd < c48 ? cnd : c48;
            widx = (int)cnd;
        }
        // cross-wave merge through LDS (packed u64; ~idx => min idx on value tie)
        unsigned long long vp =
            ((unsigned long long)(unsigned)__float_as_int(m) << 32) | (unsigned)(~widx);
        int par = t & 1;
        if (lane == 0) svbuf[par][wid] = vp;
        __syncthreads();
        const ulonglong2* sp = (const ulonglong2*)svbuf[par];
        ulonglong2 q0 = sp[0], q1 = sp[1];
        unsigned long long best = u64max(u64max(q0.x, q0.y), u64max(q1.x, q1.y));
        int bsel = (int)(~(unsigned)best);
        float4 cc = Pc[bsel];
        cx = cc.x; cy = cc.y; cz = cc.z;
        if (tid == 0) fbuf[t] = bsel;
    }
    __syncthreads();
    int* fidx = (int*)(ws + WS_FPS) + b * SS;
    for (int j = tid; j < SS; j += 256) fidx[j] = fbuf[j];
}

// ---------------- K5: 16-NN + group + maxpool (4 lanes per centroid) ----------------
__global__ __launch_bounds__(256) void k5_group(const float* __restrict__ xin,
                                                float* __restrict__ ws) {
    __shared__ float4 Pq[NN];            // 64 KB: x,y,z,|p|^2
    __shared__ float2 cand[64][65];      // 33.3 KB (pad 65 to break bank stride)
    __shared__ int    fin[64][16];       // 4 KB
    int blk = blockIdx.x, tid = threadIdx.x;
    int b = blk >> 5;                    // 32 blocks per batch
    const float* xb = xin + (size_t)b * NN * 3;
    for (int j = tid; j < NN; j += 256) {
        float x = xb[3 * j], y = xb[3 * j + 1], z = xb[3 * j + 2];
        Pq[j] = make_float4(x, y, z, (x * x + y * y) + z * z);
    }
    __syncthreads();
    int cl = tid >> 2, q = tid & 3;
    int sg = blk * 64 + cl;              // global centroid id
    const int* fidx = (const int*)(ws + WS_FPS);
    int ci = fidx[sg];
    float4 c = Pq[ci];
    float an = c.w;
    float dv[16]; int di[16];
#pragma unroll
    for (int j = 0; j < 16; j++) { dv[j] = FLT_MAX; di[j] = 0x7fffffff; }
    float cmax = FLT_MAX; int cpos = 0, cidx = 0x7fffffff;
    int nbase = q << 10;
    for (int n0 = 0; n0 < 1024; n0++) {
        int n = nbase + n0;
        float4 qq = Pq[n];
        float dot = fmaf(c.z, qq.z, fmaf(c.y, qq.y, c.x * qq.x));
        float dd = (an + qq.w) - 2.f * dot;
        if (dd < cmax) {                 // ascending n within chunk => strict < exact
#pragma unroll
            for (int j = 0; j < 16; j++) {
                bool sel = (j == cpos);
                dv[j] = sel ? dd : dv[j];
                di[j] = sel ? n : di[j];
            }
            cmax = dv[0]; cidx = di[0]; cpos = 0;
#pragma unroll
            for (int j = 1; j < 16; j++) {
                bool bt = (dv[j] > cmax) || ((dv[j] == cmax) && (di[j] > cidx));
                cmax = bt ? dv[j] : cmax; cidx = bt ? di[j] : cidx; cpos = bt ? j : cpos;
            }
        }
    }
#pragma unroll
    for (int j = 0; j < 16; j++)
        cand[cl][q * 16 + j] = make_float2(dv[j], __int_as_float(di[j]));
    __syncthreads();
    if (tid < 64) {                      // phase 2: merge 64 -> 16
        float mv[16]; int mi[16];
#pragma unroll
        for (int j = 0; j < 16; j++) { mv[j] = FLT_MAX; mi[j] = 0x7fffffff; }
        float mx = FLT_MAX; int mp = 0, mxi = 0x7fffffff;
        for (int k = 0; k < 64; k++) {
            float2 e = cand[tid][k];
            float d = e.x; int i = __float_as_int(e.y);
            if (d < mx || (d == mx && i < mxi)) {   // lexicographic entry test
#pragma unroll
                for (int j = 0; j < 16; j++) {
                    bool sel = (j == mp);
                    mv[j] = sel ? d : mv[j];
                    mi[j] = sel ? i : mi[j];
                }
                mx = mv[0]; mxi = mi[0]; mp = 0;
#pragma unroll
                for (int j = 1; j < 16; j++) {
                    bool bt = (mv[j] > mx) || ((mv[j] == mx) && (mi[j] > mxi));
                    mx = bt ? mv[j] : mx; mxi = bt ? mi[j] : mxi; mp = bt ? j : mp;
                }
            }
        }
#pragma unroll
        for (int j = 0; j < 16; j++) fin[tid][j] = mi[j];
    }
    __syncthreads();
    // phase 3: pooling — lane q handles 16 of the 64 feat channels
    int idxs[16];
#pragma unroll
    for (int j = 0; j < 16; j++) idxs[j] = fin[cl][j];
    const float* feats = ws + WS_FEATS + (size_t)b * NN * COUT;
    float4 acc[4];
#pragma unroll
    for (int m = 0; m < 4; m++) acc[m] = make_float4(-FLT_MAX, -FLT_MAX, -FLT_MAX, -FLT_MAX);
#pragma unroll 4
    for (int k = 0; k < 16; k++) {
        const float4* fp = (const float4*)(feats + (size_t)idxs[k] * COUT) + q * 4;
#pragma unroll
        for (int m = 0; m < 4; m++) {
            float4 v = fp[m];
            acc[m].x = fmaxf(acc[m].x, v.x); acc[m].y = fmaxf(acc[m].y, v.y);
            acc[m].z = fmaxf(acc[m].z, v.z); acc[m].w = fmaxf(acc[m].w, v.w);
        }
    }
    float* po = ws + WS_POOL + (size_t)sg * CAT;
#pragma unroll
    for (int m = 0; m < 4; m++) {
        int base = 3 + q * 16 + m * 4;
        po[base] = acc[m].x; po[base + 1] = acc[m].y;
        po[base + 2] = acc[m].z; po[base + 3] = acc[m].w;
    }
    if (q == 0) {
        float rx = -FLT_MAX, ry = -FLT_MAX, rz = -FLT_MAX;
#pragma unroll
        for (int k = 0; k < 16; k++) {
            float4 p = Pq[idxs[k]];
            rx = fmaxf(rx, p.x - c.x); ry = fmaxf(ry, p.y - c.y); rz = fmaxf(rz, p.z - c.z);
        }
        po[0] = rx; po[1] = ry; po[2] = rz;
    }
}

// ---------------- K6: BN2 stats over conv3 output ----------------
__global__ __launch_bounds__(256) void k6_stats2(const float* __restrict__ W3,
                                                 const float* __restrict__ b3,
                                                 float* __restrict__ ws) {
    __shared__ float W3s[64 * CAT];
    __shared__ float b3s[64];
    __shared__ float ps[128];
    int tid = threadIdx.x;
    for (int j = tid; j < 64 * CAT; j += 256) W3s[j] = W3[j];
    if (tid < 64) b3s[tid] = b3[tid];
    if (tid < 128) ps[tid] = 0.f;
    __syncthreads();
    int c = tid & 63, g = tid >> 6;
    const float* pool = ws + WS_POOL;
    float sum = 0.f, sq = 0.f;
    for (int m = 0; m < 64; m++) {
        int pt = blockIdx.x * 256 + g * 64 + m;
        const float* row = pool + (size_t)pt * CAT;
        float y = b3s[c];
        for (int j = 0; j < CAT; j++) y = fmaf(W3s[c * CAT + j], row[j], y);
        sum += y; sq = fmaf(y, y, sq);
    }
    atomicAdd(&ps[c], sum);
    atomicAdd(&ps[64 + c], sq);
    __syncthreads();
    if (tid < 128) atomicAdd(ws + WS_RED2 + tid, ps[tid]);
}

// ---------------- K8: out = conv4(relu(bn2(conv3(pooled)))), BN prep fused ----------------
__global__ __launch_bounds__(256) void k8_out(const float* __restrict__ W3,
                                              const float* __restrict__ b3,
                                              const float* __restrict__ W4,
                                              const float* __restrict__ b4,
                                              const float* __restrict__ g2,
                                              const float* __restrict__ be2,
                                              const float* __restrict__ ws,
                                              float* __restrict__ out) {
    __shared__ float W3t[CAT * 64];      // transposed: [j][o]
    __shared__ float W4s[64 * 64], b3s[64], b4s[64], ab[128];
    int tid = threadIdx.x;
    for (int lin = tid; lin < CAT * 64; lin += 256) {
        int j = lin >> 6, o = lin & 63;
        W3t[lin] = W3[o * CAT + j];
    }
    for (int j = tid; j < 4096; j += 256) W4s[j] = W4[j];
    if (tid < 64) {
        b3s[tid] = b3[tid]; b4s[tid] = b4[tid];
        float inv = 1.f / (float)M2;
        float mean = ws[WS_RED2 + tid] * inv;
        float var = ws[WS_RED2 + 64 + tid] * inv - mean * mean;
        float a = g2[tid] * rsqrtf(var + EPSB);
        ab[tid] = a;
        ab[64 + tid] = be2[tid] - mean * a;
    }
    __syncthreads();
    int pt = blockIdx.x * 256 + tid;
    const float* row = ws + WS_POOL + (size_t)pt * CAT;
    float h[64];
#pragma unroll
    for (int c = 0; c < 64; c++) h[c] = b3s[c];
    for (int j = 0; j < CAT; j++) {
        float pj = row[j];
#pragma unroll
        for (int c = 0; c < 64; c++) h[c] = fmaf(W3t[j * 64 + c], pj, h[c]);
    }
#pragma unroll
    for (int c = 0; c < 64; c++) h[c] = fmaxf(0.f, fmaf(ab[c], h[c], ab[64 + c]));
    float* op = out + (size_t)pt * 64;
    for (int o = 0; o < 64; o += 4) {
        float a0 = b4s[o], a1v = b4s[o + 1], a2v = b4s[o + 2], a3v = b4s[o + 3];
#pragma unroll
        for (int c = 0; c < 64; c++) {
            float hv = h[c];
            a0  = fmaf(W4s[(o)     * 64 + c], hv, a0);
            a1v = fmaf(W4s[(o + 1) * 64 + c], hv, a1v);
            a2v = fmaf(W4s[(o + 2) * 64 + c], hv, a2v);
            a3v = fmaf(W4s[(o + 3) * 64 + c], hv, a3v);
        }
        *(float4*)(op + o) = make_float4(a0, a1v, a2v, a3v);
    }
}

extern "C" void kernel_launch(void* const* d_in, const int* in_sizes, int n_in,
                              void* d_out, int out_size, void* d_ws, size_t ws_size,
                              hipStream_t stream) {
    (void)in_sizes; (void)n_in; (void)out_size; (void)ws_size;
    const float* xin = (const float*)d_in[0];
    const float* W1  = (const float*)d_in[1];
    const float* b1  = (const float*)d_in[2];
    const float* g1  = (const float*)d_in[3];
    const float* be1 = (const float*)d_in[4];
    const float* W2  = (const float*)d_in[5];
    const float* b2  = (const float*)d_in[6];
    const float* W3  = (const float*)d_in[7];
    const float* b3  = (const float*)d_in[8];
    const float* g2  = (const float*)d_in[9];
    const float* be2 = (const float*)d_in[10];
    const float* W4  = (const float*)d_in[11];
    const float* b4  = (const float*)d_in[12];
    float* ws = (float*)d_ws;
    float* out = (float*)d_out;
    (void)b1;

    hipMemsetAsync(d_ws, 0, (WS_RED2 + 128) * sizeof(float), stream);
    hipLaunchKernelGGL(k1_stats,  dim3(64),  dim3(256), 0, stream, xin, ws);
    hipLaunchKernelGGL(k3_feats,  dim3(128), dim3(256), 0, stream, xin, W1, b1, g1, be1, W2, b2, ws);
    hipLaunchKernelGGL(k4_fps,    dim3(8),   dim3(256), 0, stream, xin, ws);
    hipLaunchKernelGGL(k5_group,  dim3(256), dim3(256), 0, stream, xin, ws);
    hipLaunchKernelGGL(k6_stats2, dim3(64),  dim3(256), 0, stream, W3, b3, ws);
    hipLaunchKernelGGL(k8_out,    dim3(64),  dim3(256), 0, stream, W3, b3, W4, b4, g2, be2, ws, out);
}

// Round 6
// 2879.512 us; speedup vs baseline: 1.0229x; 1.0229x over previous
//
#include <hip/hip_runtime.h>
#include <hip/hip_cooperative_groups.h>
#include <float.h>

namespace cg = cooperative_groups;

#define BB   8
#define NN   4096
#define SS   2048
#define KK   16
#define MID  32
#define COUT 64
#define CAT  67            // 3 + 64
#define M1   (BB*NN)       // 32768
#define M2   (BB*SS)       // 16384
#define EPSB 1e-5f

// ---- workspace layout (float offsets) ----
#define WS_RED1  0                       // 64 blocks x 9 moment partials
#define WS_RED2  1024                    // 256 blocks x 128 BN2 partials
#define WS_FPS   33792                   // 16384 ints
#define WS_FEATS 50176                   // 32768*64 floats
#define WS_POOL  (WS_FEATS + M1*COUT)    // 16384*67 floats

// ---- shared-memory union (max phase = 118 KB -> 1 block/CU) ----
struct SA { float red[4][9]; };
struct SB4 {
    float4 Pc[NN];                                   // 64 KB
    alignas(16) unsigned long long sv[2][4];
    int fbuf[SS];                                    // 8 KB
};
struct SB3 { float W1s[96]; float abv[64]; float W2s[2048]; float b2s[64]; float mom[9]; };
struct SC {
    float4 Pq[NN];                                   // 64 KB
    float2 cand[64][65];                             // 33 KB
    int    fin[64][16];                              // 4 KB
    float  W3s[64 * CAT]; float b3s[64]; float ps[128];
};
struct SE { float W3t[CAT * 64]; float W4s[4096]; float b3s[64]; float b4s[64]; float ab[128]; };
union SU { SA a; SB4 b4; SB3 b3; SC c; SE e; };

__device__ __forceinline__ unsigned long long u64max(unsigned long long a,
                                                     unsigned long long b) {
    return a > b ? a : b;
}

template <int CTRL>
__device__ __forceinline__ float dppmaxf(float v) {
    int o = __builtin_amdgcn_update_dpp(0, __float_as_int(v), CTRL, 0xF, 0xF, false);
    return fmaxf(v, __int_as_float(o));
}

template <int CTRL>
__device__ __forceinline__ unsigned dppminu(unsigned v) {
    unsigned o = (unsigned)__builtin_amdgcn_update_dpp(0, (int)v, CTRL, 0xF, 0xF, false);
    return v < o ? v : o;
}

__global__ __launch_bounds__(256) void fused(
        const float* __restrict__ xin,
        const float* __restrict__ W1, const float* __restrict__ b1,
        const float* __restrict__ g1, const float* __restrict__ be1,
        const float* __restrict__ W2, const float* __restrict__ b2,
        const float* __restrict__ W3, const float* __restrict__ b3,
        const float* __restrict__ g2, const float* __restrict__ be2,
        const float* __restrict__ W4, const float* __restrict__ b4,
        float* __restrict__ ws, float* __restrict__ out) {
    cg::grid_group grid = cg::this_grid();
    __shared__ SU sm;
    int blk = blockIdx.x, tid = threadIdx.x;
    (void)b1;

    //================ Phase A: BN1 input moments (blocks 0-63) ================
    if (blk < 64) {
        int t = blk * 256 + tid;
        float r[9];
#pragma unroll
        for (int q = 0; q < 9; q++) r[q] = 0.f;
        for (int p = t; p < M1; p += 64 * 256) {
            float x0 = xin[3 * p], x1 = xin[3 * p + 1], x2 = xin[3 * p + 2];
            r[0] += x0; r[1] += x1; r[2] += x2;
            r[3] = fmaf(x0, x0, r[3]); r[4] = fmaf(x0, x1, r[4]); r[5] = fmaf(x0, x2, r[5]);
            r[6] = fmaf(x1, x1, r[6]); r[7] = fmaf(x1, x2, r[7]); r[8] = fmaf(x2, x2, r[8]);
        }
#pragma unroll
        for (int m = 32; m; m >>= 1) {
#pragma unroll
            for (int q = 0; q < 9; q++) r[q] += __shfl_down(r[q], m, 64);
        }
        if ((tid & 63) == 0) {
#pragma unroll
            for (int q = 0; q < 9; q++) sm.a.red[tid >> 6][q] = r[q];
        }
        __syncthreads();
        if (tid == 0) {
#pragma unroll
            for (int q = 0; q < 9; q++)
                ws[WS_RED1 + blk * 9 + q] =
                    (sm.a.red[0][q] + sm.a.red[1][q]) + (sm.a.red[2][q] + sm.a.red[3][q]);
        }
    }
    grid.sync();

    //================ Phase B: FPS (blocks 0-7) || feats (blocks 8-135) ================
    if (blk < 8) {
        int b = blk;
        const float* xb = xin + (size_t)b * NN * 3;
        float px[16], py[16], pz[16], dist[16];
#pragma unroll
        for (int k = 0; k < 16; k++) {
            int i = tid + (k << 8);
            float x = xb[3 * i], y = xb[3 * i + 1], z = xb[3 * i + 2];
            px[k] = x; py[k] = y; pz[k] = z; dist[k] = FLT_MAX;
            sm.b4.Pc[i] = make_float4(x, y, z, 0.f);
        }
        if (tid == 0) sm.b4.fbuf[0] = 0;
        __syncthreads();
        float4 c0 = sm.b4.Pc[0];
        float cx = c0.x, cy = c0.y, cz = c0.z;
        int wid = tid >> 6, lane = tid & 63;
        int a16 = ((lane ^ 16) << 2), a32 = ((lane ^ 32) << 2), a48 = ((lane ^ 48) << 2);
        for (int t = 1; t < SS; t++) {
            float nd[16];
#pragma unroll
            for (int k = 0; k < 16; k++) {
                float dx = px[k] - cx, dy = py[k] - cy, dz = pz[k] - cz;
                float d = fmaf(dz, dz, fmaf(dy, dy, dx * dx));
                nd[k] = fminf(dist[k], d);
                dist[k] = nd[k];
            }
            float v[8]; int ki[8];
#pragma unroll
            for (int j = 0; j < 8; j++) {
                bool s = nd[j + 8] > nd[j];
                v[j] = s ? nd[j + 8] : nd[j]; ki[j] = s ? j + 8 : j;
            }
#pragma unroll
            for (int j = 0; j < 4; j++) {
                bool s = v[j + 4] > v[j];
                v[j] = s ? v[j + 4] : v[j]; ki[j] = s ? ki[j + 4] : ki[j];
            }
            { bool s = v[2] > v[0]; v[0] = s ? v[2] : v[0]; ki[0] = s ? ki[2] : ki[0]; }
            { bool s = v[3] > v[1]; v[1] = s ? v[3] : v[1]; ki[1] = s ? ki[3] : ki[1]; }
            bool s01 = v[1] > v[0];
            float bv = s01 ? v[1] : v[0];
            int   bk = s01 ? ki[1] : ki[0];
            int bi = tid + (bk << 8);
            float m = bv;
            m = dppmaxf<0xB1>(m);
            m = dppmaxf<0x4E>(m);
            m = dppmaxf<0x141>(m);
            m = dppmaxf<0x140>(m);
            int mi = __float_as_int(m);
            int r16 = __builtin_amdgcn_ds_bpermute(a16, mi);
            int r32 = __builtin_amdgcn_ds_bpermute(a32, mi);
            int r48 = __builtin_amdgcn_ds_bpermute(a48, mi);
            m = fmaxf(fmaxf(m, __int_as_float(r16)),
                      fmaxf(__int_as_float(r32), __int_as_float(r48)));
            unsigned long long mask = __ballot(bv == m);
            int widx;
            if (__popcll(mask) == 1) {
                int w = __ffsll(mask) - 1;
                widx = __builtin_amdgcn_readlane(bi, w);
            } else {
                unsigned cnd = (bv == m) ? (unsigned)bi : 0xffffffffu;
                cnd = dppminu<0xB1>(cnd); cnd = dppminu<0x4E>(cnd);
                cnd = dppminu<0x141>(cnd); cnd = dppminu<0x140>(cnd);
                unsigned c16 = (unsigned)__builtin_amdgcn_ds_bpermute(a16, (int)cnd);
                unsigned c32 = (unsigned)__builtin_amdgcn_ds_bpermute(a32, (int)cnd);
                unsigned c48 = (unsigned)__builtin_amdgcn_ds_bpermute(a48, (int)cnd);
                cnd = cnd < c16 ? cnd : c16;
                cnd = cnd < c32 ? cnd : c32;
                cnd = cnd < c48 ? cnd : c48;
                widx = (int)cnd;
            }
            unsigned long long vp =
                ((unsigned long long)(unsigned)__float_as_int(m) << 32) | (unsigned)(~widx);
            int par = t & 1;
            if (lane == 0) sm.b4.sv[par][wid] = vp;
            __syncthreads();
            const ulonglong2* sp = (const ulonglong2*)sm.b4.sv[par];
            ulonglong2 q0 = sp[0], q1 = sp[1];
            unsigned long long best = u64max(u64max(q0.x, q0.y), u64max(q1.x, q1.y));
            int bsel = (int)(~(unsigned)best);
            float4 cc = sm.b4.Pc[bsel];
            cx = cc.x; cy = cc.y; cz = cc.z;
            if (tid == 0) sm.b4.fbuf[t] = bsel;
        }
        __syncthreads();
        int* fidx = (int*)(ws + WS_FPS) + b * SS;
        for (int j = tid; j < SS; j += 256) fidx[j] = sm.b4.fbuf[j];
    } else if (blk < 136) {
        for (int j = tid; j < 96; j += 256) sm.b3.W1s[j] = W1[j];
        if (tid < 64) sm.b3.b2s[tid] = b2[tid];
        for (int j = tid; j < 2048; j += 256) sm.b3.W2s[j] = W2[j];
        if (tid < 9) {
            float s = 0.f;
            for (int k = 0; k < 64; k++) s += ws[WS_RED1 + k * 9 + tid];
            sm.b3.mom[tid] = s;
        }
        __syncthreads();
        if (tid < MID) {
            float S0 = sm.b3.mom[0], S1 = sm.b3.mom[1], S2 = sm.b3.mom[2];
            float C00 = sm.b3.mom[3], C01 = sm.b3.mom[4], C02 = sm.b3.mom[5];
            float C11 = sm.b3.mom[6], C12 = sm.b3.mom[7], C22 = sm.b3.mom[8];
            float w0 = W1[3 * tid], w1 = W1[3 * tid + 1], w2 = W1[3 * tid + 2];
            float invM = 1.f / (float)M1;
            float meanc = (w0 * S0 + w1 * S1 + w2 * S2) * invM;
            float wCw = w0 * w0 * C00 + w1 * w1 * C11 + w2 * w2 * C22 +
                        2.f * (w0 * w1 * C01 + w0 * w2 * C02 + w1 * w2 * C12);
            float var = wCw * invM - meanc * meanc;
            float a = g1[tid] * rsqrtf(var + EPSB);
            sm.b3.abv[tid] = a;
            sm.b3.abv[MID + tid] = be1[tid] - meanc * a;
        }
        __syncthreads();
        int p = (blk - 8) * 256 + tid;
        float x0 = xin[3 * p], x1 = xin[3 * p + 1], x2 = xin[3 * p + 2];
        float h[MID];
#pragma unroll
        for (int o = 0; o < MID; o++) {
            float y = fmaf(sm.b3.W1s[3 * o + 2], x2,
                     fmaf(sm.b3.W1s[3 * o + 1], x1, sm.b3.W1s[3 * o] * x0));
            h[o] = fmaxf(0.f, fmaf(sm.b3.abv[o], y, sm.b3.abv[MID + o]));
        }
        float* fo = ws + WS_FEATS + (size_t)p * COUT;
#pragma unroll
        for (int j = 0; j < COUT; j += 4) {
            float a0 = sm.b3.b2s[j], a1v = sm.b3.b2s[j + 1];
            float a2v = sm.b3.b2s[j + 2], a3v = sm.b3.b2s[j + 3];
#pragma unroll
            for (int o = 0; o < MID; o++) {
                float hv = h[o];
                a0  = fmaf(sm.b3.W2s[(j)     * MID + o], hv, a0);
                a1v = fmaf(sm.b3.W2s[(j + 1) * MID + o], hv, a1v);
                a2v = fmaf(sm.b3.W2s[(j + 2) * MID + o], hv, a2v);
                a3v = fmaf(sm.b3.W2s[(j + 3) * MID + o], hv, a3v);
            }
            *(float4*)(fo + j) = make_float4(a0, a1v, a2v, a3v);
        }
    }
    grid.sync();

    //================ Phase C: 16-NN + group + maxpool + BN2 partial stats (all blocks) ================
    {
        int b = blk >> 5;
        const float* xb = xin + (size_t)b * NN * 3;
        for (int j = tid; j < NN; j += 256) {
            float x = xb[3 * j], y = xb[3 * j + 1], z = xb[3 * j + 2];
            sm.c.Pq[j] = make_float4(x, y, z, (x * x + y * y) + z * z);
        }
        for (int j = tid; j < 64 * CAT; j += 256) sm.c.W3s[j] = W3[j];
        if (tid < 64) sm.c.b3s[tid] = b3[tid];
        if (tid < 128) sm.c.ps[tid] = 0.f;
        __syncthreads();
        int cl = tid >> 2, q = tid & 3;
        int sg = blk * 64 + cl;
        const int* fidx = (const int*)(ws + WS_FPS);
        int ci = fidx[sg];
        float4 c = sm.c.Pq[ci];
        float an = c.w;
        float dv[16]; int di[16];
#pragma unroll
        for (int j = 0; j < 16; j++) { dv[j] = FLT_MAX; di[j] = 0x7fffffff; }
        float cmax = FLT_MAX; int cpos = 0, cidx = 0x7fffffff;
        int nbase = q << 10;
        for (int n0 = 0; n0 < 1024; n0++) {
            int n = nbase + n0;
            float4 qq = sm.c.Pq[n];
            float dot = fmaf(c.z, qq.z, fmaf(c.y, qq.y, c.x * qq.x));
            float dd = (an + qq.w) - 2.f * dot;
            if (dd < cmax) {
#pragma unroll
                for (int j = 0; j < 16; j++) {
                    bool sel = (j == cpos);
                    dv[j] = sel ? dd : dv[j];
                    di[j] = sel ? n : di[j];
                }
                cmax = dv[0]; cidx = di[0]; cpos = 0;
#pragma unroll
                for (int j = 1; j < 16; j++) {
                    bool bt = (dv[j] > cmax) || ((dv[j] == cmax) && (di[j] > cidx));
                    cmax = bt ? dv[j] : cmax; cidx = bt ? di[j] : cidx; cpos = bt ? j : cpos;
                }
            }
        }
#pragma unroll
        for (int j = 0; j < 16; j++)
            sm.c.cand[cl][q * 16 + j] = make_float2(dv[j], __int_as_float(di[j]));
        __syncthreads();
        if (tid < 64) {
            float mv[16]; int mi[16];
#pragma unroll
            for (int j = 0; j < 16; j++) { mv[j] = FLT_MAX; mi[j] = 0x7fffffff; }
            float mx = FLT_MAX; int mp = 0, mxi = 0x7fffffff;
            for (int k = 0; k < 64; k++) {
                float2 e = sm.c.cand[tid][k];
                float d = e.x; int i = __float_as_int(e.y);
                if (d < mx || (d == mx && i < mxi)) {
#pragma unroll
                    for (int j = 0; j < 16; j++) {
                        bool sel = (j == mp);
                        mv[j] = sel ? d : mv[j];
                        mi[j] = sel ? i : mi[j];
                    }
                    mx = mv[0]; mxi = mi[0]; mp = 0;
#pragma unroll
                    for (int j = 1; j < 16; j++) {
                        bool bt = (mv[j] > mx) || ((mv[j] == mx) && (mi[j] > mxi));
                        mx = bt ? mv[j] : mx; mxi = bt ? mi[j] : mxi; mp = bt ? j : mp;
                    }
                }
            }
#pragma unroll
            for (int j = 0; j < 16; j++) sm.c.fin[tid][j] = mi[j];
        }
        __syncthreads();
        int idxs[16];
#pragma unroll
        for (int j = 0; j < 16; j++) idxs[j] = sm.c.fin[cl][j];
        const float* feats = ws + WS_FEATS + (size_t)b * NN * COUT;
        float4 acc[4];
#pragma unroll
        for (int m = 0; m < 4; m++) acc[m] = make_float4(-FLT_MAX, -FLT_MAX, -FLT_MAX, -FLT_MAX);
#pragma unroll 4
        for (int k = 0; k < 16; k++) {
            const float4* fp = (const float4*)(feats + (size_t)idxs[k] * COUT) + q * 4;
#pragma unroll
            for (int m = 0; m < 4; m++) {
                float4 v = fp[m];
                acc[m].x = fmaxf(acc[m].x, v.x); acc[m].y = fmaxf(acc[m].y, v.y);
                acc[m].z = fmaxf(acc[m].z, v.z); acc[m].w = fmaxf(acc[m].w, v.w);
            }
        }
        float* po = ws + WS_POOL + (size_t)sg * CAT;
#pragma unroll
        for (int m = 0; m < 4; m++) {
            int base = 3 + q * 16 + m * 4;
            po[base] = acc[m].x; po[base + 1] = acc[m].y;
            po[base + 2] = acc[m].z; po[base + 3] = acc[m].w;
        }
        if (q == 0) {
            float rx = -FLT_MAX, ry = -FLT_MAX, rz = -FLT_MAX;
#pragma unroll
            for (int k = 0; k < 16; k++) {
                float4 p = sm.c.Pq[idxs[k]];
                rx = fmaxf(rx, p.x - c.x); ry = fmaxf(ry, p.y - c.y); rz = fmaxf(rz, p.z - c.z);
            }
            po[0] = rx; po[1] = ry; po[2] = rz;
        }
        __threadfence();
        __syncthreads();
        // BN2 partial stats over this block's own 64 pooled rows
        int cch = tid & 63, g = tid >> 6;
        const float* prow = ws + WS_POOL + (size_t)(blk * 64) * CAT;
        float sum = 0.f, sq = 0.f;
        for (int m = 0; m < 16; m++) {
            const float* row = prow + (size_t)(g * 16 + m) * CAT;
            float y = sm.c.b3s[cch];
            for (int j = 0; j < CAT; j++) y = fmaf(sm.c.W3s[cch * CAT + j], row[j], y);
            sum += y; sq = fmaf(y, y, sq);
        }
        atomicAdd(&sm.c.ps[cch], sum);
        atomicAdd(&sm.c.ps[64 + cch], sq);
        __syncthreads();
        if (tid < 128) ws[WS_RED2 + blk * 128 + tid] = sm.c.ps[tid];
    }
    grid.sync();

    //================ Phase D: final MLP (blocks 0-63) ================
    if (blk < 64) {
        for (int lin = tid; lin < CAT * 64; lin += 256) {
            int j = lin >> 6, o = lin & 63;
            sm.e.W3t[lin] = W3[o * CAT + j];
        }
        for (int j = tid; j < 4096; j += 256) sm.e.W4s[j] = W4[j];
        if (tid < 64) {
            sm.e.b3s[tid] = b3[tid]; sm.e.b4s[tid] = b4[tid];
            float s = 0.f, q2 = 0.f;
            for (int k = 0; k < 256; k++) {
                s  += ws[WS_RED2 + k * 128 + tid];
                q2 += ws[WS_RED2 + k * 128 + 64 + tid];
            }
            float inv = 1.f / (float)M2;
            float mean = s * inv;
            float var = q2 * inv - mean * mean;
            float a = g2[tid] * rsqrtf(var + EPSB);
            sm.e.ab[tid] = a;
            sm.e.ab[64 + tid] = be2[tid] - mean * a;
        }
        __syncthreads();
        int pt = blk * 256 + tid;
        const float* row = ws + WS_POOL + (size_t)pt * CAT;
        float h[64];
#pragma unroll
        for (int c = 0; c < 64; c++) h[c] = sm.e.b3s[c];
        for (int j = 0; j < CAT; j++) {
            float pj = row[j];
#pragma unroll
            for (int c = 0; c < 64; c++) h[c] = fmaf(sm.e.W3t[j * 64 + c], pj, h[c]);
        }
#pragma unroll
        for (int c = 0; c < 64; c++) h[c] = fmaxf(0.f, fmaf(sm.e.ab[c], h[c], sm.e.ab[64 + c]));
        float* op = out + (size_t)pt * 64;
        for (int o = 0; o < 64; o += 4) {
            float a0 = sm.e.b4s[o], a1v = sm.e.b4s[o + 1];
            float a2v = sm.e.b4s[o + 2], a3v = sm.e.b4s[o + 3];
#pragma unroll
            for (int c = 0; c < 64; c++) {
                float hv = h[c];
                a0  = fmaf(sm.e.W4s[(o)     * 64 + c], hv, a0);
                a1v = fmaf(sm.e.W4s[(o + 1) * 64 + c], hv, a1v);
                a2v = fmaf(sm.e.W4s[(o + 2) * 64 + c], hv, a2v);
                a3v = fmaf(sm.e.W4s[(o + 3) * 64 + c], hv, a3v);
            }
            *(float4*)(op + o) = make_float4(a0, a1v, a2v, a3v);
        }
    }
}

extern "C" void kernel_launch(void* const* d_in, const int* in_sizes, int n_in,
                              void* d_out, int out_size, void* d_ws, size_t ws_size,
                              hipStream_t stream) {
    (void)in_sizes; (void)n_in; (void)out_size; (void)ws_size;
    const float* xin = (const float*)d_in[0];
    const float* W1  = (const float*)d_in[1];
    const float* b1  = (const float*)d_in[2];
    const float* g1  = (const float*)d_in[3];
    const float* be1 = (const float*)d_in[4];
    const float* W2  = (const float*)d_in[5];
    const float* b2  = (const float*)d_in[6];
    const float* W3  = (const float*)d_in[7];
    const float* b3  = (const float*)d_in[8];
    const float* g2  = (const float*)d_in[9];
    const float* be2 = (const float*)d_in[10];
    const float* W4  = (const float*)d_in[11];
    const float* b4  = (const float*)d_in[12];
    float* ws  = (float*)d_ws;
    float* out = (float*)d_out;

    void* args[] = {
        (void*)&xin, (void*)&W1, (void*)&b1, (void*)&g1, (void*)&be1,
        (void*)&W2, (void*)&b2, (void*)&W3, (void*)&b3, (void*)&g2,
        (void*)&be2, (void*)&W4, (void*)&b4, (void*)&ws, (void*)&out
    };
    hipLaunchCooperativeKernel((const void*)fused, dim3(256), dim3(256),
                               args, 0, stream);
}

// Round 7
// 2361.462 us; speedup vs baseline: 1.2473x; 1.2194x over previous
//
#include <hip/hip_runtime.h>
#include <float.h>

#define BB   8
#define NN   4096
#define SS   2048
#define KK   16
#define MID  32
#define COUT 64
#define CAT  67            // 3 + 64
#define M1   (BB*NN)       // 32768
#define M2   (BB*SS)       // 16384
#define EPSB 1e-5f

// ---- workspace layout (float offsets) ----
#define WS_CTR   0                       // 8 ints: barrier counters
#define WS_RED1  16                      // 64 blocks x 9 moment partials
#define WS_RED2  640                     // 128 floats BN2 sums (atomic)
#define WS_FPS   1024                    // 16384 ints
#define WS_FEATS (1024 + 16384)          // 32768*64 floats
#define WS_POOL  (WS_FEATS + M1*COUT)    // 16384*67 floats

// ---- shared memory union (max = phase C ~136 KB -> 1 block/CU) ----
struct SA  { float red[8][9]; };
struct SB4 { float4 Pc[NN]; alignas(16) unsigned long long sv[2][8]; };
struct SB3 { float W1s[96]; float abv[64]; float W2s[2048]; float b2s[64]; float mom[9]; };
struct SC  { float4 Pq[NN]; unsigned candd[64][129]; unsigned candi[64][129]; int fin[64][16]; };
struct SC2 { float W3s[64 * CAT]; float b3s[64]; float ps[128]; };
struct SE  { float W3t[CAT * 64]; float W4s[4096]; float b3s[64]; float b4s[64]; float ab[128]; };
union  SU  { SA a; SB4 b4; SB3 b3; SC c; SC2 c2; SE e; };

__device__ __forceinline__ unsigned long long u64max(unsigned long long a,
                                                     unsigned long long b) {
    return a > b ? a : b;
}

template <int CTRL>
__device__ __forceinline__ unsigned long long dpp_swap_max(unsigned long long v) {
    int lo = (int)(unsigned)v;
    int hi = (int)(unsigned)(v >> 32);
    int olo = __builtin_amdgcn_update_dpp(0, lo, CTRL, 0xF, 0xF, false);
    int ohi = __builtin_amdgcn_update_dpp(0, hi, CTRL, 0xF, 0xF, false);
    unsigned long long ov = ((unsigned long long)(unsigned)ohi << 32) | (unsigned)olo;
    return u64max(v, ov);
}

// sleepy device-scope single-use barrier: low-rate polling (s_sleep) to avoid
// the hot-cacheline spin that grid.sync() inflicts on long unbalanced phases
__device__ __forceinline__ void barrier_join(int* ctr, int target) {
    __syncthreads();
    if (threadIdx.x == 0) {
        __threadfence();
        atomicAdd(ctr, 1);
        while (atomicAdd(ctr, 0) < target) __builtin_amdgcn_s_sleep(16);
        __threadfence();
    }
    __syncthreads();
}

__global__ __launch_bounds__(512) void fused(
        const float* __restrict__ xin,
        const float* __restrict__ W1, const float* __restrict__ b1,
        const float* __restrict__ g1, const float* __restrict__ be1,
        const float* __restrict__ W2, const float* __restrict__ b2,
        const float* __restrict__ W3, const float* __restrict__ b3,
        const float* __restrict__ g2, const float* __restrict__ be2,
        const float* __restrict__ W4, const float* __restrict__ b4,
        float* __restrict__ ws, float* __restrict__ out) {
    __shared__ SU sm;
    int blk = blockIdx.x, tid = threadIdx.x;
    int* ctr = (int*)ws;
    (void)b1;

    //===== Phase A: BN1 input moments (blocks 8-71; others just arrive) =====
    if (blk >= 8) {
        if (blk < 72) {
            int p = (blk - 8) * 512 + tid;    // exactly one point per thread
            float x0 = xin[3 * p], x1 = xin[3 * p + 1], x2 = xin[3 * p + 2];
            float r[9];
            r[0] = x0; r[1] = x1; r[2] = x2;
            r[3] = x0 * x0; r[4] = x0 * x1; r[5] = x0 * x2;
            r[6] = x1 * x1; r[7] = x1 * x2; r[8] = x2 * x2;
#pragma unroll
            for (int m = 32; m; m >>= 1) {
#pragma unroll
                for (int q = 0; q < 9; q++) r[q] += __shfl_down(r[q], m, 64);
            }
            if ((tid & 63) == 0) {
#pragma unroll
                for (int q = 0; q < 9; q++) sm.a.red[tid >> 6][q] = r[q];
            }
            __syncthreads();
            if (tid == 0) {
#pragma unroll
                for (int q = 0; q < 9; q++) {
                    float s = 0.f;
#pragma unroll
                    for (int w = 0; w < 8; w++) s += sm.a.red[w][q];
                    ws[WS_RED1 + (blk - 8) * 9 + q] = s;
                }
            }
        }
        barrier_join(ctr + 0, 248);
    }

    //===== Phase B: FPS (blocks 0-7, R3-exact 512thr) || feats (blocks 8-71) =====
    if (blk < 8) {
        int b = blk;
        const float* xb = xin + (size_t)b * NN * 3;
        float px[8], py[8], pz[8], dist[8];
#pragma unroll
        for (int k = 0; k < 8; k++) {
            int i = tid + (k << 9);
            float x = xb[3 * i], y = xb[3 * i + 1], z = xb[3 * i + 2];
            px[k] = x; py[k] = y; pz[k] = z; dist[k] = FLT_MAX;
            sm.b4.Pc[i] = make_float4(x, y, z, 0.f);
        }
        int* fidx = (int*)(ws + WS_FPS) + b * SS;
        if (tid == 0) fidx[0] = 0;
        __syncthreads();
        float4 c0 = sm.b4.Pc[0];
        float cx = c0.x, cy = c0.y, cz = c0.z;
        int wid = tid >> 6, lane = tid & 63;
        for (int t = 1; t < SS; t++) {
            float bv = -1.f; int bi = 0;
#pragma unroll
            for (int k = 0; k < 8; k++) {
                float dx = px[k] - cx, dy = py[k] - cy, dz = pz[k] - cz;
                float d = fmaf(dz, dz, fmaf(dy, dy, dx * dx));
                float nd = fminf(dist[k], d);
                dist[k] = nd;
                bool bt = nd > bv;
                bv = bt ? nd : bv; bi = bt ? (tid + (k << 9)) : bi;
            }
            unsigned long long v =
                ((unsigned long long)__float_as_uint(bv) << 32) | (unsigned)(~bi);
            v = dpp_swap_max<0xB1>(v);
            v = dpp_swap_max<0x4E>(v);
            v = dpp_swap_max<0x141>(v);
            v = dpp_swap_max<0x140>(v);
            {
                int a16 = ((lane ^ 16) << 2), a32 = ((lane ^ 32) << 2), a48 = ((lane ^ 48) << 2);
                int lo = (int)(unsigned)v, hi = (int)(unsigned)(v >> 32);
                int lo16 = __builtin_amdgcn_ds_bpermute(a16, lo);
                int hi16 = __builtin_amdgcn_ds_bpermute(a16, hi);
                int lo32 = __builtin_amdgcn_ds_bpermute(a32, lo);
                int hi32 = __builtin_amdgcn_ds_bpermute(a32, hi);
                int lo48 = __builtin_amdgcn_ds_bpermute(a48, lo);
                int hi48 = __builtin_amdgcn_ds_bpermute(a48, hi);
                unsigned long long v16 = ((unsigned long long)(unsigned)hi16 << 32) | (unsigned)lo16;
                unsigned long long v32 = ((unsigned long long)(unsigned)hi32 << 32) | (unsigned)lo32;
                unsigned long long v48 = ((unsigned long long)(unsigned)hi48 << 32) | (unsigned)lo48;
                v = u64max(u64max(v, v16), u64max(v32, v48));
            }
            int par = t & 1;
            if (lane == 0) sm.b4.sv[par][wid] = v;
            __syncthreads();
            const ulonglong2* sp = (const ulonglong2*)sm.b4.sv[par];
            ulonglong2 q0 = sp[0], q1 = sp[1], q2 = sp[2], q3 = sp[3];
            unsigned long long m0 = u64max(q0.x, q0.y), m1 = u64max(q1.x, q1.y);
            unsigned long long m2 = u64max(q2.x, q2.y), m3 = u64max(q3.x, q3.y);
            unsigned long long best = u64max(u64max(m0, m1), u64max(m2, m3));
            int bsel = (int)(~(unsigned)best);
            float4 cc = sm.b4.Pc[bsel];
            cx = cc.x; cy = cc.y; cz = cc.z;
            if (tid == 0) fidx[t] = bsel;
        }
    } else if (blk < 72) {
        for (int j = tid; j < 96; j += 512) sm.b3.W1s[j] = W1[j];
        if (tid < 64) sm.b3.b2s[tid] = b2[tid];
        for (int j = tid; j < 2048; j += 512) sm.b3.W2s[j] = W2[j];
        if (tid < 9) {
            float s = 0.f;
            for (int k = 0; k < 64; k++) s += ws[WS_RED1 + k * 9 + tid];
            sm.b3.mom[tid] = s;
        }
        __syncthreads();
        if (tid < MID) {
            float S0 = sm.b3.mom[0], S1 = sm.b3.mom[1], S2 = sm.b3.mom[2];
            float C00 = sm.b3.mom[3], C01 = sm.b3.mom[4], C02 = sm.b3.mom[5];
            float C11 = sm.b3.mom[6], C12 = sm.b3.mom[7], C22 = sm.b3.mom[8];
            float w0 = W1[3 * tid], w1 = W1[3 * tid + 1], w2 = W1[3 * tid + 2];
            float invM = 1.f / (float)M1;
            float meanc = (w0 * S0 + w1 * S1 + w2 * S2) * invM;
            float wCw = w0 * w0 * C00 + w1 * w1 * C11 + w2 * w2 * C22 +
                        2.f * (w0 * w1 * C01 + w0 * w2 * C02 + w1 * w2 * C12);
            float var = wCw * invM - meanc * meanc;
            float a = g1[tid] * rsqrtf(var + EPSB);
            sm.b3.abv[tid] = a;
            sm.b3.abv[MID + tid] = be1[tid] - meanc * a;
        }
        __syncthreads();
        int p = (blk - 8) * 512 + tid;
        float x0 = xin[3 * p], x1 = xin[3 * p + 1], x2 = xin[3 * p + 2];
        float h[MID];
#pragma unroll
        for (int o = 0; o < MID; o++) {
            float y = fmaf(sm.b3.W1s[3 * o + 2], x2,
                     fmaf(sm.b3.W1s[3 * o + 1], x1, sm.b3.W1s[3 * o] * x0));
            h[o] = fmaxf(0.f, fmaf(sm.b3.abv[o], y, sm.b3.abv[MID + o]));
        }
        float* fo = ws + WS_FEATS + (size_t)p * COUT;
#pragma unroll
        for (int j = 0; j < COUT; j += 4) {
            float a0 = sm.b3.b2s[j], a1v = sm.b3.b2s[j + 1];
            float a2v = sm.b3.b2s[j + 2], a3v = sm.b3.b2s[j + 3];
#pragma unroll
            for (int o = 0; o < MID; o++) {
                float hv = h[o];
                a0  = fmaf(sm.b3.W2s[(j)     * MID + o], hv, a0);
                a1v = fmaf(sm.b3.W2s[(j + 1) * MID + o], hv, a1v);
                a2v = fmaf(sm.b3.W2s[(j + 2) * MID + o], hv, a2v);
                a3v = fmaf(sm.b3.W2s[(j + 3) * MID + o], hv, a3v);
            }
            *(float4*)(fo + j) = make_float4(a0, a1v, a2v, a3v);
        }
    }
    barrier_join(ctr + 1, 256);

    //===== Phase C: 16-NN + group + maxpool (all blocks, 8 lanes/centroid) =====
    {
        int b = blk >> 5;
        const float* xb = xin + (size_t)b * NN * 3;
        for (int j = tid; j < NN; j += 512) {
            float x = xb[3 * j], y = xb[3 * j + 1], z = xb[3 * j + 2];
            sm.c.Pq[j] = make_float4(x, y, z, (x * x + y * y) + z * z);
        }
        __syncthreads();
        int cl = tid >> 3, q = tid & 7;
        int sg = blk * 64 + cl;
        const int* fidx = (const int*)(ws + WS_FPS);
        int ci = fidx[sg];
        float4 c = sm.c.Pq[ci];
        float an = c.w;
        unsigned long long cv[16];
#pragma unroll
        for (int j = 0; j < 16; j++) cv[j] = ~0ULL;
        unsigned long long cmaxv = ~0ULL; int cpos = 0;
        for (int n0 = 0; n0 < 512; n0++) {
            int n = (q << 9) + ((n0 + q) & 511);       // bank-staggered
            float4 qq = sm.c.Pq[n];
            float dot = fmaf(c.z, qq.z, fmaf(c.y, qq.y, c.x * qq.x));
            float dd = (an + qq.w) - 2.f * dot;        // same fp as ref expansion
            unsigned db = __float_as_uint(dd);
            db ^= (unsigned)(((int)db >> 31) | 0x80000000u);   // sortable bits
            unsigned long long newv = ((unsigned long long)db << 32) | (unsigned)n;
            if (newv < cmaxv) {                        // lexicographic (d, idx)
#pragma unroll
                for (int j = 0; j < 16; j++) cv[j] = (j == cpos) ? newv : cv[j];
                unsigned long long m1a[8]; int p1a[8];
#pragma unroll
                for (int j = 0; j < 8; j++) {
                    bool s = cv[2 * j + 1] > cv[2 * j];
                    m1a[j] = s ? cv[2 * j + 1] : cv[2 * j];
                    p1a[j] = s ? 2 * j + 1 : 2 * j;
                }
                unsigned long long m2a[4]; int p2a[4];
#pragma unroll
                for (int j = 0; j < 4; j++) {
                    bool s = m1a[2 * j + 1] > m1a[2 * j];
                    m2a[j] = s ? m1a[2 * j + 1] : m1a[2 * j];
                    p2a[j] = s ? p1a[2 * j + 1] : p1a[2 * j];
                }
                unsigned long long m3a, m3b; int p3a, p3b;
                { bool s = m2a[1] > m2a[0]; m3a = s ? m2a[1] : m2a[0]; p3a = s ? p2a[1] : p2a[0]; }
                { bool s = m2a[3] > m2a[2]; m3b = s ? m2a[3] : m2a[2]; p3b = s ? p2a[3] : p2a[2]; }
                bool s = m3b > m3a;
                cmaxv = s ? m3b : m3a; cpos = s ? p3b : p3a;
            }
        }
#pragma unroll
        for (int j = 0; j < 16; j++) {
            sm.c.candd[cl][q * 16 + j] = (unsigned)(cv[j] >> 32);
            sm.c.candi[cl][q * 16 + j] = (unsigned)cv[j];
        }
        __syncthreads();
        if (tid < 64) {                                // merge 128 -> 16
            unsigned long long mv[16];
#pragma unroll
            for (int j = 0; j < 16; j++) mv[j] = ~0ULL;
            unsigned long long mx = ~0ULL; int mp = 0;
            for (int k = 0; k < 128; k++) {
                unsigned long long e =
                    ((unsigned long long)sm.c.candd[tid][k] << 32) | sm.c.candi[tid][k];
                if (e < mx) {
#pragma unroll
                    for (int j = 0; j < 16; j++) mv[j] = (j == mp) ? e : mv[j];
                    unsigned long long m1a[8]; int p1a[8];
#pragma unroll
                    for (int j = 0; j < 8; j++) {
                        bool s = mv[2 * j + 1] > mv[2 * j];
                        m1a[j] = s ? mv[2 * j + 1] : mv[2 * j];
                        p1a[j] = s ? 2 * j + 1 : 2 * j;
                    }
                    unsigned long long m2a[4]; int p2a[4];
#pragma unroll
                    for (int j = 0; j < 4; j++) {
                        bool s = m1a[2 * j + 1] > m1a[2 * j];
                        m2a[j] = s ? m1a[2 * j + 1] : m1a[2 * j];
                        p2a[j] = s ? p1a[2 * j + 1] : p1a[2 * j];
                    }
                    unsigned long long m3a, m3b; int p3a, p3b;
                    { bool s = m2a[1] > m2a[0]; m3a = s ? m2a[1] : m2a[0]; p3a = s ? p2a[1] : p2a[0]; }
                    { bool s = m2a[3] > m2a[2]; m3b = s ? m2a[3] : m2a[2]; p3b = s ? p2a[3] : p2a[2]; }
                    bool s = m3b > m3a;
                    mx = s ? m3b : m3a; mp = s ? p3b : p3a;
                }
            }
#pragma unroll
            for (int j = 0; j < 16; j++) sm.c.fin[tid][j] = (int)(unsigned)mv[j];
        }
        __syncthreads();
        int idxs[16];
#pragma unroll
        for (int j = 0; j < 16; j++) idxs[j] = sm.c.fin[cl][j];
        const float* feats = ws + WS_FEATS + (size_t)b * NN * COUT;
        float4 acc0 = make_float4(-FLT_MAX, -FLT_MAX, -FLT_MAX, -FLT_MAX);
        float4 acc1 = acc0;
#pragma unroll 4
        for (int k = 0; k < 16; k++) {
            const float4* fp = (const float4*)(feats + (size_t)idxs[k] * COUT) + q * 2;
            float4 v0 = fp[0], v1 = fp[1];
            acc0.x = fmaxf(acc0.x, v0.x); acc0.y = fmaxf(acc0.y, v0.y);
            acc0.z = fmaxf(acc0.z, v0.z); acc0.w = fmaxf(acc0.w, v0.w);
            acc1.x = fmaxf(acc1.x, v1.x); acc1.y = fmaxf(acc1.y, v1.y);
            acc1.z = fmaxf(acc1.z, v1.z); acc1.w = fmaxf(acc1.w, v1.w);
        }
        float* po = ws + WS_POOL + (size_t)sg * CAT + 3 + q * 8;
        po[0] = acc0.x; po[1] = acc0.y; po[2] = acc0.z; po[3] = acc0.w;
        po[4] = acc1.x; po[5] = acc1.y; po[6] = acc1.z; po[7] = acc1.w;
        if (q == 0) {
            float rx = -FLT_MAX, ry = -FLT_MAX, rz = -FLT_MAX;
#pragma unroll
            for (int k = 0; k < 16; k++) {
                float4 p = sm.c.Pq[idxs[k]];
                rx = fmaxf(rx, p.x - c.x); ry = fmaxf(ry, p.y - c.y); rz = fmaxf(rz, p.z - c.z);
            }
            float* pb = ws + WS_POOL + (size_t)sg * CAT;
            pb[0] = rx; pb[1] = ry; pb[2] = rz;
        }
    }
    barrier_join(ctr + 2, 256);

    //===== Phase C2: BN2 stats (blocks 0-63) =====
    if (blk < 64) {
        for (int j = tid; j < 64 * CAT; j += 512) sm.c2.W3s[j] = W3[j];
        if (tid < 64) sm.c2.b3s[tid] = b3[tid];
        if (tid < 128) sm.c2.ps[tid] = 0.f;
        __syncthreads();
        int cch = tid & 63, g = tid >> 6;    // 8 groups x 32 rows
        float sum = 0.f, sq = 0.f;
        for (int m = 0; m < 32; m++) {
            int row = blk * 256 + g * 32 + m;
            const float* r = ws + WS_POOL + (size_t)row * CAT;
            float y = sm.c2.b3s[cch];
            for (int j = 0; j < CAT; j++) y = fmaf(sm.c2.W3s[cch * CAT + j], r[j], y);
            sum += y; sq = fmaf(y, y, sq);
        }
        atomicAdd(&sm.c2.ps[cch], sum);
        atomicAdd(&sm.c2.ps[64 + cch], sq);
        __syncthreads();
        if (tid < 128) atomicAdd(ws + WS_RED2 + tid, sm.c2.ps[tid]);
    }
    barrier_join(ctr + 3, 256);

    //===== Phase D: final MLP (blocks 0-31) =====
    if (blk < 32) {
        for (int lin = tid; lin < CAT * 64; lin += 512) {
            int j = lin >> 6, o = lin & 63;
            sm.e.W3t[lin] = W3[o * CAT + j];
        }
        for (int j = tid; j < 4096; j += 512) sm.e.W4s[j] = W4[j];
        if (tid < 64) {
            sm.e.b3s[tid] = b3[tid]; sm.e.b4s[tid] = b4[tid];
            float inv = 1.f / (float)M2;
            float mean = ws[WS_RED2 + tid] * inv;
            float var = ws[WS_RED2 + 64 + tid] * inv - mean * mean;
            float a = g2[tid] * rsqrtf(var + EPSB);
            sm.e.ab[tid] = a;
            sm.e.ab[64 + tid] = be2[tid] - mean * a;
        }
        __syncthreads();
        int pt = blk * 512 + tid;
        const float* row = ws + WS_POOL + (size_t)pt * CAT;
        float h[64];
#pragma unroll
        for (int c = 0; c < 64; c++) h[c] = sm.e.b3s[c];
        for (int j = 0; j < CAT; j++) {
            float pj = row[j];
#pragma unroll
            for (int c = 0; c < 64; c++) h[c] = fmaf(sm.e.W3t[j * 64 + c], pj, h[c]);
        }
#pragma unroll
        for (int c = 0; c < 64; c++) h[c] = fmaxf(0.f, fmaf(sm.e.ab[c], h[c], sm.e.ab[64 + c]));
        float* op = out + (size_t)pt * 64;
        for (int o = 0; o < 64; o += 4) {
            float a0 = sm.e.b4s[o], a1v = sm.e.b4s[o + 1];
            float a2v = sm.e.b4s[o + 2], a3v = sm.e.b4s[o + 3];
#pragma unroll
            for (int c = 0; c < 64; c++) {
                float hv = h[c];
                a0  = fmaf(sm.e.W4s[(o)     * 64 + c], hv, a0);
                a1v = fmaf(sm.e.W4s[(o + 1) * 64 + c], hv, a1v);
                a2v = fmaf(sm.e.W4s[(o + 2) * 64 + c], hv, a2v);
                a3v = fmaf(sm.e.W4s[(o + 3) * 64 + c], hv, a3v);
            }
            *(float4*)(op + o) = make_float4(a0, a1v, a2v, a3v);
        }
    }
}

extern "C" void kernel_launch(void* const* d_in, const int* in_sizes, int n_in,
                              void* d_out, int out_size, void* d_ws, size_t ws_size,
                              hipStream_t stream) {
    (void)in_sizes; (void)n_in; (void)out_size; (void)ws_size;
    const float* xin = (const float*)d_in[0];
    const float* W1  = (const float*)d_in[1];
    const float* b1  = (const float*)d_in[2];
    const float* g1  = (const float*)d_in[3];
    const float* be1 = (const float*)d_in[4];
    const float* W2  = (const float*)d_in[5];
    const float* b2  = (const float*)d_in[6];
    const float* W3  = (const float*)d_in[7];
    const float* b3  = (const float*)d_in[8];
    const float* g2  = (const float*)d_in[9];
    const float* be2 = (const float*)d_in[10];
    const float* W4  = (const float*)d_in[11];
    const float* b4  = (const float*)d_in[12];
    float* ws  = (float*)d_ws;
    float* out = (float*)d_out;

    hipMemsetAsync(d_ws, 0, 4096, stream);   // barrier counters + stat accumulators
    void* args[] = {
        (void*)&xin, (void*)&W1, (void*)&b1, (void*)&g1, (void*)&be1,
        (void*)&W2, (void*)&b2, (void*)&W3, (void*)&b3, (void*)&g2,
        (void*)&be2, (void*)&W4, (void*)&b4, (void*)&ws, (void*)&out
    };
    hipLaunchCooperativeKernel((const void*)fused, dim3(256), dim3(512),
                               args, 0, stream);
}

// Round 8
// 2181.578 us; speedup vs baseline: 1.3502x; 1.0825x over previous
//
#include <hip/hip_runtime.h>
#include <float.h>

#define BB   8
#define NN   4096
#define SS   2048
#define MID  32
#define COUT 64
#define CAT  67            // 3 + 64
#define M1   (BB*NN)       // 32768
#define M2   (BB*SS)       // 16384
#define EPSB 1e-5f
#define NCHUNK 64          // 64 chunks of 32 centroids per batch
#define CSZ    32

// ---- workspace layout ----
// int offsets (ws as int*):
#define WI_CTR   0                       // 4 barrier counters
#define WI_TKT   4                       // ticket counter
#define WI_PROG  8                       // 8 per-batch FPS progress
// float offsets (ws as float*):
#define WS_RED2  32                      // 128 floats BN2 sums (atomic)
#define WS_RED1  160                     // 64 blocks x 9 moment partials
#define WS_FPS   1024                    // 16384 ints
#define WS_FEATS (1024 + 16384)          // 32768*64 floats
#define WS_POOL  (WS_FEATS + M1*COUT)    // 16384*67 floats

// ---- shared memory union (max = SC ~133 KB -> 1 block/CU) ----
struct SA  { float red[8][9]; };
struct SB4 { float4 Pc[NN]; alignas(16) unsigned long long sv[2][8]; };
struct SB3 { float W1s[96]; float abv[64]; float W2s[2048]; float b2s[64]; float mom[9]; };
struct SC  { float4 Pq[NN]; unsigned long long cand[CSZ][257]; int fin[CSZ][16]; int tkt; };
struct SC2 { float W3s[64 * CAT]; float b3s[64]; float ps[128]; };
struct SE  { float W3t[CAT * 64]; float W4s[4096]; float b3s[64]; float b4s[64]; float ab[128]; };
union  SU  { SA a; SB4 b4; SB3 b3; SC c; SC2 c2; SE e; };

__device__ __forceinline__ unsigned long long u64max(unsigned long long a,
                                                     unsigned long long b) {
    return a > b ? a : b;
}

template <int CTRL>
__device__ __forceinline__ unsigned long long dpp_swap_max(unsigned long long v) {
    int lo = (int)(unsigned)v;
    int hi = (int)(unsigned)(v >> 32);
    int olo = __builtin_amdgcn_update_dpp(0, lo, CTRL, 0xF, 0xF, false);
    int ohi = __builtin_amdgcn_update_dpp(0, hi, CTRL, 0xF, 0xF, false);
    unsigned long long ov = ((unsigned long long)(unsigned)ohi << 32) | (unsigned)olo;
    return u64max(v, ov);
}

// sleepy single-use device barrier (R7-proven)
__device__ __forceinline__ void barrier_join(int* ctr, int target) {
    __syncthreads();
    if (threadIdx.x == 0) {
        __threadfence();
        atomicAdd(ctr, 1);
        while (atomicAdd(ctr, 0) < target) __builtin_amdgcn_s_sleep(16);
        __threadfence();
    }
    __syncthreads();
}

// keep smallest-16 u64 keys; cmaxv/cpos track current max slot
__device__ __forceinline__ void top16_insert(unsigned long long* cv,
                                             unsigned long long newv,
                                             unsigned long long& cmaxv, int& cpos) {
#pragma unroll
    for (int j = 0; j < 16; j++) cv[j] = (j == cpos) ? newv : cv[j];
    unsigned long long m1a[8]; int p1a[8];
#pragma unroll
    for (int j = 0; j < 8; j++) {
        bool s = cv[2 * j + 1] > cv[2 * j];
        m1a[j] = s ? cv[2 * j + 1] : cv[2 * j];
        p1a[j] = s ? 2 * j + 1 : 2 * j;
    }
    unsigned long long m2a[4]; int p2a[4];
#pragma unroll
    for (int j = 0; j < 4; j++) {
        bool s = m1a[2 * j + 1] > m1a[2 * j];
        m2a[j] = s ? m1a[2 * j + 1] : m1a[2 * j];
        p2a[j] = s ? p1a[2 * j + 1] : p1a[2 * j];
    }
    unsigned long long m3a, m3b; int p3a, p3b;
    { bool s = m2a[1] > m2a[0]; m3a = s ? m2a[1] : m2a[0]; p3a = s ? p2a[1] : p2a[0]; }
    { bool s = m2a[3] > m2a[2]; m3b = s ? m2a[3] : m2a[2]; p3b = s ? p2a[3] : p2a[2]; }
    bool s = m3b > m3a;
    cmaxv = s ? m3b : m3a; cpos = s ? p3b : p3a;
}

__global__ __launch_bounds__(512) void fused(
        const float* __restrict__ xin,
        const float* __restrict__ W1, const float* __restrict__ b1,
        const float* __restrict__ g1, const float* __restrict__ be1,
        const float* __restrict__ W2, const float* __restrict__ b2,
        const float* __restrict__ W3, const float* __restrict__ b3,
        const float* __restrict__ g2, const float* __restrict__ be2,
        const float* __restrict__ W4, const float* __restrict__ b4,
        float* __restrict__ ws, float* __restrict__ out) {
    __shared__ SU sm;
    int blk = blockIdx.x, tid = threadIdx.x;
    int* ctri  = (int*)ws;
    int* prog  = ctri + WI_PROG;
    int* fidxg = (int*)(ws + WS_FPS);
    (void)b1;

    if (blk < 8) {
        //======== FPS producer (R3-exact inner loop; atomic publishes) ========
        int b = blk;
        const float* xb = xin + (size_t)b * NN * 3;
        float px[8], py[8], pz[8], dist[8];
#pragma unroll
        for (int k = 0; k < 8; k++) {
            int i = tid + (k << 9);
            float x = xb[3 * i], y = xb[3 * i + 1], z = xb[3 * i + 2];
            px[k] = x; py[k] = y; pz[k] = z; dist[k] = FLT_MAX;
            sm.b4.Pc[i] = make_float4(x, y, z, 0.f);
        }
        if (tid == 0)
            __hip_atomic_store(fidxg + b * SS, 0, __ATOMIC_RELAXED, __HIP_MEMORY_SCOPE_AGENT);
        __syncthreads();
        float4 c0 = sm.b4.Pc[0];
        float cx = c0.x, cy = c0.y, cz = c0.z;
        int wid = tid >> 6, lane = tid & 63;
        for (int t = 1; t < SS; t++) {
            float bv = -1.f; int bi = 0;
#pragma unroll
            for (int k = 0; k < 8; k++) {
                float dx = px[k] - cx, dy = py[k] - cy, dz = pz[k] - cz;
                float d = fmaf(dz, dz, fmaf(dy, dy, dx * dx));
                float nd = fminf(dist[k], d);
                dist[k] = nd;
                bool bt = nd > bv;
                bv = bt ? nd : bv; bi = bt ? (tid + (k << 9)) : bi;
            }
            unsigned long long v =
                ((unsigned long long)__float_as_uint(bv) << 32) | (unsigned)(~bi);
            v = dpp_swap_max<0xB1>(v);
            v = dpp_swap_max<0x4E>(v);
            v = dpp_swap_max<0x141>(v);
            v = dpp_swap_max<0x140>(v);
            {
                int a16 = ((lane ^ 16) << 2), a32 = ((lane ^ 32) << 2), a48 = ((lane ^ 48) << 2);
                int lo = (int)(unsigned)v, hi = (int)(unsigned)(v >> 32);
                int lo16 = __builtin_amdgcn_ds_bpermute(a16, lo);
                int hi16 = __builtin_amdgcn_ds_bpermute(a16, hi);
                int lo32 = __builtin_amdgcn_ds_bpermute(a32, lo);
                int hi32 = __builtin_amdgcn_ds_bpermute(a32, hi);
                int lo48 = __builtin_amdgcn_ds_bpermute(a48, lo);
                int hi48 = __builtin_amdgcn_ds_bpermute(a48, hi);
                unsigned long long v16 = ((unsigned long long)(unsigned)hi16 << 32) | (unsigned)lo16;
                unsigned long long v32 = ((unsigned long long)(unsigned)hi32 << 32) | (unsigned)lo32;
                unsigned long long v48 = ((unsigned long long)(unsigned)hi48 << 32) | (unsigned)lo48;
                v = u64max(u64max(v, v16), u64max(v32, v48));
            }
            int par = t & 1;
            if (lane == 0) sm.b4.sv[par][wid] = v;
            __syncthreads();
            const ulonglong2* sp = (const ulonglong2*)sm.b4.sv[par];
            ulonglong2 q0 = sp[0], q1 = sp[1], q2 = sp[2], q3 = sp[3];
            unsigned long long m0 = u64max(q0.x, q0.y), m1 = u64max(q1.x, q1.y);
            unsigned long long m2 = u64max(q2.x, q2.y), m3 = u64max(q3.x, q3.y);
            unsigned long long best = u64max(u64max(m0, m1), u64max(m2, m3));
            int bsel = (int)(~(unsigned)best);
            float4 cc = sm.b4.Pc[bsel];
            cx = cc.x; cy = cc.y; cz = cc.z;
            if (tid == 0) {
                __hip_atomic_store(fidxg + b * SS + t, bsel,
                                   __ATOMIC_RELAXED, __HIP_MEMORY_SCOPE_AGENT);
                if (((t + 1) & (CSZ - 1)) == 0)
                    __hip_atomic_store(prog + b, t + 1,
                                       __ATOMIC_RELEASE, __HIP_MEMORY_SCOPE_AGENT);
            }
        }
        barrier_join(ctri + 2, 256);
    } else {
        //======== Phase A: BN1 moments (blocks 8-71) ========
        if (blk < 72) {
            int p = (blk - 8) * 512 + tid;
            float x0 = xin[3 * p], x1 = xin[3 * p + 1], x2 = xin[3 * p + 2];
            float r[9];
            r[0] = x0; r[1] = x1; r[2] = x2;
            r[3] = x0 * x0; r[4] = x0 * x1; r[5] = x0 * x2;
            r[6] = x1 * x1; r[7] = x1 * x2; r[8] = x2 * x2;
#pragma unroll
            for (int m = 32; m; m >>= 1) {
#pragma unroll
                for (int q = 0; q < 9; q++) r[q] += __shfl_down(r[q], m, 64);
            }
            if ((tid & 63) == 0) {
#pragma unroll
                for (int q = 0; q < 9; q++) sm.a.red[tid >> 6][q] = r[q];
            }
            __syncthreads();
            if (tid == 0) {
#pragma unroll
                for (int q = 0; q < 9; q++) {
                    float s = 0.f;
#pragma unroll
                    for (int w = 0; w < 8; w++) s += sm.a.red[w][q];
                    ws[WS_RED1 + (blk - 8) * 9 + q] = s;
                }
            }
            barrier_join(ctri + 0, 64);
            //======== feats = conv2(relu(bn(conv1))) (blocks 8-71) ========
            for (int j = tid; j < 96; j += 512) sm.b3.W1s[j] = W1[j];
            if (tid < 64) sm.b3.b2s[tid] = b2[tid];
            for (int j = tid; j < 2048; j += 512) sm.b3.W2s[j] = W2[j];
            if (tid < 9) {
                float s = 0.f;
                for (int k = 0; k < 64; k++) s += ws[WS_RED1 + k * 9 + tid];
                sm.b3.mom[tid] = s;
            }
            __syncthreads();
            if (tid < MID) {
                float S0 = sm.b3.mom[0], S1 = sm.b3.mom[1], S2 = sm.b3.mom[2];
                float C00 = sm.b3.mom[3], C01 = sm.b3.mom[4], C02 = sm.b3.mom[5];
                float C11 = sm.b3.mom[6], C12 = sm.b3.mom[7], C22 = sm.b3.mom[8];
                float w0 = W1[3 * tid], w1 = W1[3 * tid + 1], w2 = W1[3 * tid + 2];
                float invM = 1.f / (float)M1;
                float meanc = (w0 * S0 + w1 * S1 + w2 * S2) * invM;
                float wCw = w0 * w0 * C00 + w1 * w1 * C11 + w2 * w2 * C22 +
                            2.f * (w0 * w1 * C01 + w0 * w2 * C02 + w1 * w2 * C12);
                float var = wCw * invM - meanc * meanc;
                float a = g1[tid] * rsqrtf(var + EPSB);
                sm.b3.abv[tid] = a;
                sm.b3.abv[MID + tid] = be1[tid] - meanc * a;
            }
            __syncthreads();
            int p2 = (blk - 8) * 512 + tid;
            float y0 = xin[3 * p2], y1 = xin[3 * p2 + 1], y2 = xin[3 * p2 + 2];
            float h[MID];
#pragma unroll
            for (int o = 0; o < MID; o++) {
                float y = fmaf(sm.b3.W1s[3 * o + 2], y2,
                         fmaf(sm.b3.W1s[3 * o + 1], y1, sm.b3.W1s[3 * o] * y0));
                h[o] = fmaxf(0.f, fmaf(sm.b3.abv[o], y, sm.b3.abv[MID + o]));
            }
            float* fo = ws + WS_FEATS + (size_t)p2 * COUT;
#pragma unroll
            for (int j = 0; j < COUT; j += 4) {
                float a0 = sm.b3.b2s[j], a1v = sm.b3.b2s[j + 1];
                float a2v = sm.b3.b2s[j + 2], a3v = sm.b3.b2s[j + 3];
#pragma unroll
                for (int o = 0; o < MID; o++) {
                    float hv = h[o];
                    a0  = fmaf(sm.b3.W2s[(j)     * MID + o], hv, a0);
                    a1v = fmaf(sm.b3.W2s[(j + 1) * MID + o], hv, a1v);
                    a2v = fmaf(sm.b3.W2s[(j + 2) * MID + o], hv, a2v);
                    a3v = fmaf(sm.b3.W2s[(j + 3) * MID + o], hv, a3v);
                }
                *(float4*)(fo + j) = make_float4(a0, a1v, a2v, a3v);
            }
        }
        barrier_join(ctri + 1, 248);   // feats visible to all consumers

        //======== Pipelined NN+pool: ticket queue over 512 chunks ========
        int curb = -1;
        for (;;) {
            if (tid == 0) sm.c.tkt = atomicAdd(ctri + WI_TKT, 1);
            __syncthreads();             // also protects fin/cand reuse
            int tk = sm.c.tkt;
            if (tk >= BB * NCHUNK) break;
            int b = tk & 7, c = tk >> 3;
            if (b != curb) {             // load Pq for this batch
                const float* xb = xin + (size_t)b * NN * 3;
                for (int j = tid; j < NN; j += 512) {
                    float x = xb[3 * j], y = xb[3 * j + 1], z = xb[3 * j + 2];
                    sm.c.Pq[j] = make_float4(x, y, z, (x * x + y * y) + z * z);
                }
                curb = b;
            }
            if (tid == 0) {              // wait for FPS prefix
                int need = (c + 1) * CSZ;
                while (__hip_atomic_load(prog + b, __ATOMIC_ACQUIRE,
                                         __HIP_MEMORY_SCOPE_AGENT) < need)
                    __builtin_amdgcn_s_sleep(8);
            }
            __syncthreads();
            int cc = tid >> 4, q = tid & 15;    // 32 centroids x 16 lanes
            int s = c * CSZ + cc;
            int sg = b * SS + s;
            int ci = __hip_atomic_load(fidxg + sg, __ATOMIC_RELAXED,
                                       __HIP_MEMORY_SCOPE_AGENT);
            float4 cen = sm.c.Pq[ci];
            float an = cen.w;
            unsigned long long cv[16];
#pragma unroll
            for (int j = 0; j < 16; j++) cv[j] = ~0ULL;
            unsigned long long cmaxv = ~0ULL; int cpos = 0;
            for (int n0 = 0; n0 < 256; n0++) {
                int n = (q << 8) + ((n0 + q) & 255);          // bank-staggered
                float4 qq = sm.c.Pq[n];
                float dot = fmaf(cen.z, qq.z, fmaf(cen.y, qq.y, cen.x * qq.x));
                float dd = (an + qq.w) - 2.f * dot;
                unsigned db = __float_as_uint(dd);
                db ^= (unsigned)(((int)db >> 31) | 0x80000000u);
                unsigned long long newv = ((unsigned long long)db << 32) | (unsigned)n;
                if (newv < cmaxv) top16_insert(cv, newv, cmaxv, cpos);
            }
#pragma unroll
            for (int j = 0; j < 16; j++) sm.c.cand[cc][q * 16 + j] = cv[j];
            __syncthreads();
            if (tid < CSZ) {             // merge 256 -> 16 per centroid
                unsigned long long mv[16];
#pragma unroll
                for (int j = 0; j < 16; j++) mv[j] = ~0ULL;
                unsigned long long mx = ~0ULL; int mp = 0;
                for (int k = 0; k < 256; k++) {
                    unsigned long long e = sm.c.cand[tid][k];
                    if (e < mx) top16_insert(mv, e, mx, mp);
                }
#pragma unroll
                for (int j = 0; j < 16; j++) sm.c.fin[tid][j] = (int)(unsigned)mv[j];
            }
            __syncthreads();
            int idxs[16];
#pragma unroll
            for (int j = 0; j < 16; j++) idxs[j] = sm.c.fin[cc][j];
            const float* feats = ws + WS_FEATS + (size_t)b * NN * COUT;
            float4 acc = make_float4(-FLT_MAX, -FLT_MAX, -FLT_MAX, -FLT_MAX);
#pragma unroll 4
            for (int k = 0; k < 16; k++) {
                const float4* fp = (const float4*)(feats + (size_t)idxs[k] * COUT) + q;
                float4 v0 = fp[0];
                acc.x = fmaxf(acc.x, v0.x); acc.y = fmaxf(acc.y, v0.y);
                acc.z = fmaxf(acc.z, v0.z); acc.w = fmaxf(acc.w, v0.w);
            }
            float* po = ws + WS_POOL + (size_t)sg * CAT;
            po[3 + q * 4] = acc.x; po[4 + q * 4] = acc.y;
            po[5 + q * 4] = acc.z; po[6 + q * 4] = acc.w;
            if (q == 0) {
                float rx = -FLT_MAX, ry = -FLT_MAX, rz = -FLT_MAX;
#pragma unroll
                for (int k = 0; k < 16; k++) {
                    float4 p = sm.c.Pq[idxs[k]];
                    rx = fmaxf(rx, p.x - cen.x);
                    ry = fmaxf(ry, p.y - cen.y);
                    rz = fmaxf(rz, p.z - cen.z);
                }
                po[0] = rx; po[1] = ry; po[2] = rz;
            }
        }
        barrier_join(ctri + 2, 256);
    }

    //======== C2: BN2 stats (all 256 blocks, 64 rows each) ========
    {
        for (int j = tid; j < 64 * CAT; j += 512) sm.c2.W3s[j] = W3[j];
        if (tid < 64) sm.c2.b3s[tid] = b3[tid];
        if (tid < 128) sm.c2.ps[tid] = 0.f;
        __syncthreads();
        int cch = tid & 63, g = tid >> 6;   // 8 row-groups x 8 rows
        float sum = 0.f, sq = 0.f;
        for (int m = 0; m < 8; m++) {
            int row = blk * 64 + g * 8 + m;
            const float* r = ws + WS_POOL + (size_t)row * CAT;
            float y = sm.c2.b3s[cch];
            for (int j = 0; j < CAT; j++) y = fmaf(sm.c2.W3s[cch * CAT + j], r[j], y);
            sum += y; sq = fmaf(y, y, sq);
        }
        atomicAdd(&sm.c2.ps[cch], sum);
        atomicAdd(&sm.c2.ps[64 + cch], sq);
        __syncthreads();
        if (tid < 128) atomicAdd(ws + WS_RED2 + tid, sm.c2.ps[tid]);
    }
    barrier_join(ctri + 3, 256);

    //======== D: final MLP (all 256 blocks, 64 rows each) ========
    {
        for (int lin = tid; lin < CAT * 64; lin += 512) {
            int j = lin >> 6, o = lin & 63;
            sm.e.W3t[lin] = W3[o * CAT + j];
        }
        for (int j = tid; j < 4096; j += 512) sm.e.W4s[j] = W4[j];
        if (tid < 64) {
            sm.e.b3s[tid] = b3[tid]; sm.e.b4s[tid] = b4[tid];
            float inv = 1.f / (float)M2;
            float mean = ws[WS_RED2 + tid] * inv;
            float var = ws[WS_RED2 + 64 + tid] * inv - mean * mean;
            float a = g2[tid] * rsqrtf(var + EPSB);
            sm.e.ab[tid] = a;
            sm.e.ab[64 + tid] = be2[tid] - mean * a;
        }
        __syncthreads();
        if (tid < 64) {
            int pt = blk * 64 + tid;
            const float* row = ws + WS_POOL + (size_t)pt * CAT;
            float h[64];
#pragma unroll
            for (int c = 0; c < 64; c++) h[c] = sm.e.b3s[c];
            for (int j = 0; j < CAT; j++) {
                float pj = row[j];
#pragma unroll
                for (int c = 0; c < 64; c++) h[c] = fmaf(sm.e.W3t[j * 64 + c], pj, h[c]);
            }
#pragma unroll
            for (int c = 0; c < 64; c++)
                h[c] = fmaxf(0.f, fmaf(sm.e.ab[c], h[c], sm.e.ab[64 + c]));
            float* op = out + (size_t)pt * 64;
            for (int o = 0; o < 64; o += 4) {
                float a0 = sm.e.b4s[o], a1v = sm.e.b4s[o + 1];
                float a2v = sm.e.b4s[o + 2], a3v = sm.e.b4s[o + 3];
#pragma unroll
                for (int c = 0; c < 64; c++) {
                    float hv = h[c];
                    a0  = fmaf(sm.e.W4s[(o)     * 64 + c], hv, a0);
                    a1v = fmaf(sm.e.W4s[(o + 1) * 64 + c], hv, a1v);
                    a2v = fmaf(sm.e.W4s[(o + 2) * 64 + c], hv, a2v);
                    a3v = fmaf(sm.e.W4s[(o + 3) * 64 + c], hv, a3v);
                }
                *(float4*)(op + o) = make_float4(a0, a1v, a2v, a3v);
            }
        }
    }
}

extern "C" void kernel_launch(void* const* d_in, const int* in_sizes, int n_in,
                              void* d_out, int out_size, void* d_ws, size_t ws_size,
                              hipStream_t stream) {
    (void)in_sizes; (void)n_in; (void)out_size; (void)ws_size;
    const float* xin = (const float*)d_in[0];
    const float* W1  = (const float*)d_in[1];
    const float* b1  = (const float*)d_in[2];
    const float* g1  = (const float*)d_in[3];
    const float* be1 = (const float*)d_in[4];
    const float* W2  = (const float*)d_in[5];
    const float* b2  = (const float*)d_in[6];
    const float* W3  = (const float*)d_in[7];
    const float* b3  = (const float*)d_in[8];
    const float* g2  = (const float*)d_in[9];
    const float* be2 = (const float*)d_in[10];
    const float* W4  = (const float*)d_in[11];
    const float* b4  = (const float*)d_in[12];
    float* ws  = (float*)d_ws;
    float* out = (float*)d_out;

    hipMemsetAsync(d_ws, 0, 4096, stream);   // counters, progress, BN2 accumulators
    void* args[] = {
        (void*)&xin, (void*)&W1, (void*)&b1, (void*)&g1, (void*)&be1,
        (void*)&W2, (void*)&b2, (void*)&W3, (void*)&b3, (void*)&g2,
        (void*)&be2, (void*)&W4, (void*)&b4, (void*)&ws, (void*)&out
    };
    hipLaunchCooperativeKernel((const void*)fused, dim3(256), dim3(512),
                               args, 0, stream);
}

// Round 9
// 2097.148 us; speedup vs baseline: 1.4046x; 1.0403x over previous
//
#include <hip/hip_runtime.h>
#include <float.h>

#define BB   8
#define NN   4096
#define SS   2048
#define MID  32
#define COUT 64
#define CAT  67            // 3 + 64
#define M1   (BB*NN)       // 32768
#define M2   (BB*SS)       // 16384
#define EPSB 1e-5f
#define NCHUNK 64          // chunks per batch
#define CSZ    32          // centroids per chunk

// ---- control (int offsets; each hot word on its own 64B line) ----
#define I_B0   0
#define I_B1   16
#define I_B2   32
#define I_TKT  64
#define I_PROG 80          // + b*16
// ---- float offsets ----
#define WS_RED2  256                     // 128 floats BN2 sums (atomic)
#define WS_RED1  400                     // 64 x 9 moment partials
#define WS_FPS   1024                    // 16384 ints
#define WS_FEATS (1024 + 16384)          // 32768*64 floats
#define WS_POOL  (WS_FEATS + M1*COUT)    // 16384*67 floats

// ---- shared memory union (max = SC ~148 KB -> 1 block/CU) ----
struct SA  { float red[8][9]; };
struct SB4 { float4 Pc[NN]; alignas(16) unsigned long long sv[2][8]; };
struct SB3 { float W1s[96]; float abv[64]; float W2s[2048]; float b2s[64]; float mom[9]; };
struct SC  { float4 Pq[NN]; unsigned long long cand[CSZ][257]; int fin[CSZ][16];
             float W3s[64 * CAT]; float b3s[64]; float ps[128]; int tkt; };
struct SE  { float W3t[CAT * 64]; float W4s[4096]; float b3s[64]; float b4s[64]; float ab[128]; };
union  SU  { SA a; SB4 b4; SB3 b3; SC c; SE e; };

__device__ __forceinline__ unsigned long long u64max(unsigned long long a,
                                                     unsigned long long b) {
    return a > b ? a : b;
}

template <int CTRL>
__device__ __forceinline__ unsigned long long dpp_swap_max(unsigned long long v) {
    int lo = (int)(unsigned)v;
    int hi = (int)(unsigned)(v >> 32);
    int olo = __builtin_amdgcn_update_dpp(0, lo, CTRL, 0xF, 0xF, false);
    int ohi = __builtin_amdgcn_update_dpp(0, hi, CTRL, 0xF, 0xF, false);
    unsigned long long ov = ((unsigned long long)(unsigned)ohi << 32) | (unsigned)olo;
    return u64max(v, ov);
}

// sleepy single-use device barrier; long sleep to keep its line cold
__device__ __forceinline__ void barrier_join(int* ctr, int target) {
    __syncthreads();
    if (threadIdx.x == 0) {
        __threadfence();
        atomicAdd(ctr, 1);
        while (__hip_atomic_load(ctr, __ATOMIC_RELAXED, __HIP_MEMORY_SCOPE_AGENT) < target)
            __builtin_amdgcn_s_sleep(64);
        __threadfence();
    }
    __syncthreads();
}

// keep smallest-16 u64 keys; cmaxv/cpos track current max slot
__device__ __forceinline__ void top16_insert(unsigned long long* cv,
                                             unsigned long long newv,
                                             unsigned long long& cmaxv, int& cpos) {
#pragma unroll
    for (int j = 0; j < 16; j++) cv[j] = (j == cpos) ? newv : cv[j];
    unsigned long long m1a[8]; int p1a[8];
#pragma unroll
    for (int j = 0; j < 8; j++) {
        bool s = cv[2 * j + 1] > cv[2 * j];
        m1a[j] = s ? cv[2 * j + 1] : cv[2 * j];
        p1a[j] = s ? 2 * j + 1 : 2 * j;
    }
    unsigned long long m2a[4]; int p2a[4];
#pragma unroll
    for (int j = 0; j < 4; j++) {
        bool s = m1a[2 * j + 1] > m1a[2 * j];
        m2a[j] = s ? m1a[2 * j + 1] : m1a[2 * j];
        p2a[j] = s ? p1a[2 * j + 1] : p1a[2 * j];
    }
    unsigned long long m3a, m3b; int p3a, p3b;
    { bool s = m2a[1] > m2a[0]; m3a = s ? m2a[1] : m2a[0]; p3a = s ? p2a[1] : p2a[0]; }
    { bool s = m2a[3] > m2a[2]; m3b = s ? m2a[3] : m2a[2]; p3b = s ? p2a[3] : p2a[2]; }
    bool s = m3b > m3a;
    cmaxv = s ? m3b : m3a; cpos = s ? p3b : p3a;
}

__global__ __launch_bounds__(512) void fused(
        const float* __restrict__ xin,
        const float* __restrict__ W1, const float* __restrict__ b1,
        const float* __restrict__ g1, const float* __restrict__ be1,
        const float* __restrict__ W2, const float* __restrict__ b2,
        const float* __restrict__ W3, const float* __restrict__ b3,
        const float* __restrict__ g2, const float* __restrict__ be2,
        const float* __restrict__ W4, const float* __restrict__ b4,
        float* __restrict__ ws, float* __restrict__ out) {
    __shared__ SU sm;
    int blk = blockIdx.x, tid = threadIdx.x;
    int* ctri  = (int*)ws;
    int* fidxg = (int*)(ws + WS_FPS);
    (void)b1;

    if (blk < 8) {
        //======== FPS producer (R3 inner loop; batched int4 publishes) ========
        int b = blk;
        const float* xb = xin + (size_t)b * NN * 3;
        int* fob = fidxg + b * SS;
        int* progb = ctri + I_PROG + b * 16;
        float px[8], py[8], pz[8], dist[8];
#pragma unroll
        for (int k = 0; k < 8; k++) {
            int i = tid + (k << 9);
            float x = xb[3 * i], y = xb[3 * i + 1], z = xb[3 * i + 2];
            px[k] = x; py[k] = y; pz[k] = z; dist[k] = FLT_MAX;
            sm.b4.Pc[i] = make_float4(x, y, z, 0.f);
        }
        __syncthreads();
        float4 c0 = sm.b4.Pc[0];
        float cx = c0.x, cy = c0.y, cz = c0.z;
        int wid = tid >> 6, lane = tid & 63;
        int rbuf[8];
        rbuf[0] = 0;                       // fidx[0] = 0
        for (int t = 1; t < SS; t++) {
            float bv = -1.f; int bi = 0;
#pragma unroll
            for (int k = 0; k < 8; k++) {
                float dx = px[k] - cx, dy = py[k] - cy, dz = pz[k] - cz;
                float d = fmaf(dz, dz, fmaf(dy, dy, dx * dx));
                float nd = fminf(dist[k], d);
                dist[k] = nd;
                bool bt = nd > bv;
                bv = bt ? nd : bv; bi = bt ? (tid + (k << 9)) : bi;
            }
            unsigned long long v =
                ((unsigned long long)__float_as_uint(bv) << 32) | (unsigned)(~bi);
            v = dpp_swap_max<0xB1>(v);
            v = dpp_swap_max<0x4E>(v);
            v = dpp_swap_max<0x141>(v);
            v = dpp_swap_max<0x140>(v);
            {
                int a16 = ((lane ^ 16) << 2), a32 = ((lane ^ 32) << 2), a48 = ((lane ^ 48) << 2);
                int lo = (int)(unsigned)v, hi = (int)(unsigned)(v >> 32);
                int lo16 = __builtin_amdgcn_ds_bpermute(a16, lo);
                int hi16 = __builtin_amdgcn_ds_bpermute(a16, hi);
                int lo32 = __builtin_amdgcn_ds_bpermute(a32, lo);
                int hi32 = __builtin_amdgcn_ds_bpermute(a32, hi);
                int lo48 = __builtin_amdgcn_ds_bpermute(a48, lo);
                int hi48 = __builtin_amdgcn_ds_bpermute(a48, hi);
                unsigned long long v16 = ((unsigned long long)(unsigned)hi16 << 32) | (unsigned)lo16;
                unsigned long long v32 = ((unsigned long long)(unsigned)hi32 << 32) | (unsigned)lo32;
                unsigned long long v48 = ((unsigned long long)(unsigned)hi48 << 32) | (unsigned)lo48;
                v = u64max(u64max(v, v16), u64max(v32, v48));
            }
            int par = t & 1;
            if (lane == 0) sm.b4.sv[par][wid] = v;
            __syncthreads();
            const ulonglong2* sp = (const ulonglong2*)sm.b4.sv[par];
            ulonglong2 q0 = sp[0], q1 = sp[1], q2 = sp[2], q3 = sp[3];
            unsigned long long m0 = u64max(q0.x, q0.y), m1 = u64max(q1.x, q1.y);
            unsigned long long m2 = u64max(q2.x, q2.y), m3 = u64max(q3.x, q3.y);
            unsigned long long best = u64max(u64max(m0, m1), u64max(m2, m3));
            int bsel = (int)(~(unsigned)best);
            float4 cc = sm.b4.Pc[bsel];
            cx = cc.x; cy = cc.y; cz = cc.z;
            if (tid == 0) {
                rbuf[t & 7] = bsel;
                if ((t & 7) == 7) {
                    *(int4*)(fob + t - 7) = make_int4(rbuf[0], rbuf[1], rbuf[2], rbuf[3]);
                    *(int4*)(fob + t - 3) = make_int4(rbuf[4], rbuf[5], rbuf[6], rbuf[7]);
                    if ((t & 31) == 31)
                        __hip_atomic_store(progb, t + 1, __ATOMIC_RELEASE,
                                           __HIP_MEMORY_SCOPE_AGENT);
                }
            }
        }
        barrier_join(ctri + I_B2, 256);
    } else {
        //======== Phase A: BN1 moments (blocks 8-71) ========
        if (blk < 72) {
            int p = (blk - 8) * 512 + tid;
            float x0 = xin[3 * p], x1 = xin[3 * p + 1], x2 = xin[3 * p + 2];
            float r[9];
            r[0] = x0; r[1] = x1; r[2] = x2;
            r[3] = x0 * x0; r[4] = x0 * x1; r[5] = x0 * x2;
            r[6] = x1 * x1; r[7] = x1 * x2; r[8] = x2 * x2;
#pragma unroll
            for (int m = 32; m; m >>= 1) {
#pragma unroll
                for (int q = 0; q < 9; q++) r[q] += __shfl_down(r[q], m, 64);
            }
            if ((tid & 63) == 0) {
#pragma unroll
                for (int q = 0; q < 9; q++) sm.a.red[tid >> 6][q] = r[q];
            }
            __syncthreads();
            if (tid == 0) {
#pragma unroll
                for (int q = 0; q < 9; q++) {
                    float s = 0.f;
#pragma unroll
                    for (int w = 0; w < 8; w++) s += sm.a.red[w][q];
                    ws[WS_RED1 + (blk - 8) * 9 + q] = s;
                }
            }
            barrier_join(ctri + I_B0, 64);
            //======== feats = conv2(relu(bn(conv1))) ========
            for (int j = tid; j < 96; j += 512) sm.b3.W1s[j] = W1[j];
            if (tid < 64) sm.b3.b2s[tid] = b2[tid];
            for (int j = tid; j < 2048; j += 512) sm.b3.W2s[j] = W2[j];
            if (tid < 9) {
                float s = 0.f;
                for (int k = 0; k < 64; k++) s += ws[WS_RED1 + k * 9 + tid];
                sm.b3.mom[tid] = s;
            }
            __syncthreads();
            if (tid < MID) {
                float S0 = sm.b3.mom[0], S1 = sm.b3.mom[1], S2 = sm.b3.mom[2];
                float C00 = sm.b3.mom[3], C01 = sm.b3.mom[4], C02 = sm.b3.mom[5];
                float C11 = sm.b3.mom[6], C12 = sm.b3.mom[7], C22 = sm.b3.mom[8];
                float w0 = W1[3 * tid], w1 = W1[3 * tid + 1], w2 = W1[3 * tid + 2];
                float invM = 1.f / (float)M1;
                float meanc = (w0 * S0 + w1 * S1 + w2 * S2) * invM;
                float wCw = w0 * w0 * C00 + w1 * w1 * C11 + w2 * w2 * C22 +
                            2.f * (w0 * w1 * C01 + w0 * w2 * C02 + w1 * w2 * C12);
                float var = wCw * invM - meanc * meanc;
                float a = g1[tid] * rsqrtf(var + EPSB);
                sm.b3.abv[tid] = a;
                sm.b3.abv[MID + tid] = be1[tid] - meanc * a;
            }
            __syncthreads();
            int p2 = (blk - 8) * 512 + tid;
            float y0 = xin[3 * p2], y1 = xin[3 * p2 + 1], y2 = xin[3 * p2 + 2];
            float h[MID];
#pragma unroll
            for (int o = 0; o < MID; o++) {
                float y = fmaf(sm.b3.W1s[3 * o + 2], y2,
                         fmaf(sm.b3.W1s[3 * o + 1], y1, sm.b3.W1s[3 * o] * y0));
                h[o] = fmaxf(0.f, fmaf(sm.b3.abv[o], y, sm.b3.abv[MID + o]));
            }
            float* fo = ws + WS_FEATS + (size_t)p2 * COUT;
#pragma unroll
            for (int j = 0; j < COUT; j += 4) {
                float a0 = sm.b3.b2s[j], a1v = sm.b3.b2s[j + 1];
                float a2v = sm.b3.b2s[j + 2], a3v = sm.b3.b2s[j + 3];
#pragma unroll
                for (int o = 0; o < MID; o++) {
                    float hv = h[o];
                    a0  = fmaf(sm.b3.W2s[(j)     * MID + o], hv, a0);
                    a1v = fmaf(sm.b3.W2s[(j + 1) * MID + o], hv, a1v);
                    a2v = fmaf(sm.b3.W2s[(j + 2) * MID + o], hv, a2v);
                    a3v = fmaf(sm.b3.W2s[(j + 3) * MID + o], hv, a3v);
                }
                *(float4*)(fo + j) = make_float4(a0, a1v, a2v, a3v);
            }
        }
        barrier_join(ctri + I_B1, 248);   // feats visible to all consumers

        //======== consumer: load W3 once, then ticket loop w/ fused BN2 ========
        for (int j = tid; j < 64 * CAT; j += 512) sm.c.W3s[j] = W3[j];
        if (tid < 64) sm.c.b3s[tid] = b3[tid];
        if (tid < 128) sm.c.ps[tid] = 0.f;
        __syncthreads();
        int c0ch = (tid & 15) * 4;                      // 4 BN2 channels per thread
        float bsum[4] = {0.f, 0.f, 0.f, 0.f}, bsq[4] = {0.f, 0.f, 0.f, 0.f};
        int curb = -1;
        for (;;) {
            if (tid == 0) sm.c.tkt = atomicAdd(ctri + I_TKT, 1);
            __syncthreads();
            int tk = sm.c.tkt;
            if (tk >= BB * NCHUNK) break;
            int b = tk & 7, c = tk >> 3;
            if (b != curb) {
                const float* xb = xin + (size_t)b * NN * 3;
                for (int j = tid; j < NN; j += 512) {
                    float x = xb[3 * j], y = xb[3 * j + 1], z = xb[3 * j + 2];
                    sm.c.Pq[j] = make_float4(x, y, z, (x * x + y * y) + z * z);
                }
                curb = b;
            }
            if (tid == 0) {               // wait for FPS prefix (cold polling)
                int* progb = ctri + I_PROG + b * 16;
                int need = (c + 1) * CSZ;
                while (__hip_atomic_load(progb, __ATOMIC_RELAXED,
                                         __HIP_MEMORY_SCOPE_AGENT) < need)
                    __builtin_amdgcn_s_sleep(64);
                (void)__hip_atomic_load(progb, __ATOMIC_ACQUIRE,
                                        __HIP_MEMORY_SCOPE_AGENT);
            }
            __syncthreads();
            int cc = tid >> 4, q = tid & 15;   // 32 centroids x 16 lanes
            int s = c * CSZ + cc;
            int sg = b * SS + s;
            int ci = fidxg[sg];
            float4 cen = sm.c.Pq[ci];
            float an = cen.w;
            unsigned long long cv[16];
#pragma unroll
            for (int j = 0; j < 16; j++) cv[j] = ~0ULL;
            unsigned long long cmaxv = ~0ULL; int cpos = 0;
            for (int n0 = 0; n0 < 256; n0++) {
                int n = (q << 8) + ((n0 + q) & 255);
                float4 qq = sm.c.Pq[n];
                float dot = fmaf(cen.z, qq.z, fmaf(cen.y, qq.y, cen.x * qq.x));
                float dd = (an + qq.w) - 2.f * dot;
                unsigned db = __float_as_uint(dd);
                db ^= (unsigned)(((int)db >> 31) | 0x80000000u);
                unsigned long long newv = ((unsigned long long)db << 32) | (unsigned)n;
                if (newv < cmaxv) top16_insert(cv, newv, cmaxv, cpos);
            }
#pragma unroll
            for (int j = 0; j < 16; j++) sm.c.cand[cc][q * 16 + j] = cv[j];
            __syncthreads();
            if (tid < CSZ) {              // merge 256 -> 16 per centroid
                unsigned long long mv[16];
#pragma unroll
                for (int j = 0; j < 16; j++) mv[j] = ~0ULL;
                unsigned long long mx = ~0ULL; int mp = 0;
                for (int k = 0; k < 256; k++) {
                    unsigned long long e = sm.c.cand[tid][k];
                    if (e < mx) top16_insert(mv, e, mx, mp);
                }
#pragma unroll
                for (int j = 0; j < 16; j++) sm.c.fin[tid][j] = (int)(unsigned)mv[j];
            }
            __syncthreads();
            int idxs[16];
#pragma unroll
            for (int j = 0; j < 16; j++) idxs[j] = sm.c.fin[cc][j];
            const float* feats = ws + WS_FEATS + (size_t)b * NN * COUT;
            float4 acc = make_float4(-FLT_MAX, -FLT_MAX, -FLT_MAX, -FLT_MAX);
#pragma unroll 4
            for (int k = 0; k < 16; k++) {
                const float4* fp = (const float4*)(feats + (size_t)idxs[k] * COUT) + q;
                float4 v0 = fp[0];
                acc.x = fmaxf(acc.x, v0.x); acc.y = fmaxf(acc.y, v0.y);
                acc.z = fmaxf(acc.z, v0.z); acc.w = fmaxf(acc.w, v0.w);
            }
            float* po = ws + WS_POOL + (size_t)sg * CAT;
            po[3 + q * 4] = acc.x; po[4 + q * 4] = acc.y;
            po[5 + q * 4] = acc.z; po[6 + q * 4] = acc.w;
            if (q == 0) {
                float rx = -FLT_MAX, ry = -FLT_MAX, rz = -FLT_MAX;
#pragma unroll
                for (int k = 0; k < 16; k++) {
                    float4 p = sm.c.Pq[idxs[k]];
                    rx = fmaxf(rx, p.x - cen.x);
                    ry = fmaxf(ry, p.y - cen.y);
                    rz = fmaxf(rz, p.z - cen.z);
                }
                po[0] = rx; po[1] = ry; po[2] = rz;
            }
            __syncthreads();              // all 16 q-lanes wrote the row
            // fused BN2 partial: row (c*32 + tid>>4), channels c0ch..+3
            {
                int rrow = b * SS + c * CSZ + (tid >> 4);
                const float* rp = ws + WS_POOL + (size_t)rrow * CAT;
                float y0 = sm.c.b3s[c0ch],     y1 = sm.c.b3s[c0ch + 1];
                float y2 = sm.c.b3s[c0ch + 2], y3 = sm.c.b3s[c0ch + 3];
                for (int j = 0; j < CAT; j++) {
                    float pj = rp[j];
                    y0 = fmaf(sm.c.W3s[(c0ch)     * CAT + j], pj, y0);
                    y1 = fmaf(sm.c.W3s[(c0ch + 1) * CAT + j], pj, y1);
                    y2 = fmaf(sm.c.W3s[(c0ch + 2) * CAT + j], pj, y2);
                    y3 = fmaf(sm.c.W3s[(c0ch + 3) * CAT + j], pj, y3);
                }
                bsum[0] += y0; bsq[0] = fmaf(y0, y0, bsq[0]);
                bsum[1] += y1; bsq[1] = fmaf(y1, y1, bsq[1]);
                bsum[2] += y2; bsq[2] = fmaf(y2, y2, bsq[2]);
                bsum[3] += y3; bsq[3] = fmaf(y3, y3, bsq[3]);
            }
        }
        // flush BN2 partials: LDS reduce then 128 global atomics
#pragma unroll
        for (int u = 0; u < 4; u++) {
            atomicAdd(&sm.c.ps[c0ch + u], bsum[u]);
            atomicAdd(&sm.c.ps[64 + c0ch + u], bsq[u]);
        }
        __syncthreads();
        if (tid < 128) atomicAdd(ws + WS_RED2 + tid, sm.c.ps[tid]);
        barrier_join(ctri + I_B2, 256);
    }

    //======== D: final MLP (all 256 blocks, 64 rows each) ========
    {
        for (int lin = tid; lin < CAT * 64; lin += 512) {
            int j = lin >> 6, o = lin & 63;
            sm.e.W3t[lin] = W3[o * CAT + j];
        }
        for (int j = tid; j < 4096; j += 512) sm.e.W4s[j] = W4[j];
        if (tid < 64) {
            sm.e.b3s[tid] = b3[tid]; sm.e.b4s[tid] = b4[tid];
            float inv = 1.f / (float)M2;
            float mean = ws[WS_RED2 + tid] * inv;
            float var = ws[WS_RED2 + 64 + tid] * inv - mean * mean;
            float a = g2[tid] * rsqrtf(var + EPSB);
            sm.e.ab[tid] = a;
            sm.e.ab[64 + tid] = be2[tid] - mean * a;
        }
        __syncthreads();
        if (tid < 64) {
            int pt = blk * 64 + tid;
            const float* row = ws + WS_POOL + (size_t)pt * CAT;
            float h[64];
#pragma unroll
            for (int c = 0; c < 64; c++) h[c] = sm.e.b3s[c];
            for (int j = 0; j < CAT; j++) {
                float pj = row[j];
#pragma unroll
                for (int c = 0; c < 64; c++) h[c] = fmaf(sm.e.W3t[j * 64 + c], pj, h[c]);
            }
#pragma unroll
            for (int c = 0; c < 64; c++)
                h[c] = fmaxf(0.f, fmaf(sm.e.ab[c], h[c], sm.e.ab[64 + c]));
            float* op = out + (size_t)pt * 64;
            for (int o = 0; o < 64; o += 4) {
                float a0 = sm.e.b4s[o], a1v = sm.e.b4s[o + 1];
                float a2v = sm.e.b4s[o + 2], a3v = sm.e.b4s[o + 3];
#pragma unroll
                for (int c = 0; c < 64; c++) {
                    float hv = h[c];
                    a0  = fmaf(sm.e.W4s[(o)     * 64 + c], hv, a0);
                    a1v = fmaf(sm.e.W4s[(o + 1) * 64 + c], hv, a1v);
                    a2v = fmaf(sm.e.W4s[(o + 2) * 64 + c], hv, a2v);
                    a3v = fmaf(sm.e.W4s[(o + 3) * 64 + c], hv, a3v);
                }
                *(float4*)(op + o) = make_float4(a0, a1v, a2v, a3v);
            }
        }
    }
}

extern "C" void kernel_launch(void* const* d_in, const int* in_sizes, int n_in,
                              void* d_out, int out_size, void* d_ws, size_t ws_size,
                              hipStream_t stream) {
    (void)in_sizes; (void)n_in; (void)out_size; (void)ws_size;
    const float* xin = (const float*)d_in[0];
    const float* W1  = (const float*)d_in[1];
    const float* b1  = (const float*)d_in[2];
    const float* g1  = (const float*)d_in[3];
    const float* be1 = (const float*)d_in[4];
    const float* W2  = (const float*)d_in[5];
    const float* b2  = (const float*)d_in[6];
    const float* W3  = (const float*)d_in[7];
    const float* b3  = (const float*)d_in[8];
    const float* g2  = (const float*)d_in[9];
    const float* be2 = (const float*)d_in[10];
    const float* W4  = (const float*)d_in[11];
    const float* b4  = (const float*)d_in[12];
    float* ws  = (float*)d_ws;
    float* out = (float*)d_out;

    hipMemsetAsync(d_ws, 0, 4096, stream);   // control lines + BN2/moment accumulators
    void* args[] = {
        (void*)&xin, (void*)&W1, (void*)&b1, (void*)&g1, (void*)&be1,
        (void*)&W2, (void*)&b2, (void*)&W3, (void*)&b3, (void*)&g2,
        (void*)&be2, (void*)&W4, (void*)&b4, (void*)&ws, (void*)&out
    };
    hipLaunchCooperativeKernel((const void*)fused, dim3(256), dim3(512),
                               args, 0, stream);
}